// Round 1
// baseline (654.274 us; speedup 1.0000x reference)
//
#include <hip/hip_runtime.h>

#define R_ 64
#define C_ 512
#define E_ 768
#define H_ 12
#define D_ 64
#define M_TOT (R_*C_)   // 32768

using short8  = __attribute__((ext_vector_type(8))) short;
using f32x4   = __attribute__((ext_vector_type(4))) float;
using floatv4 = __attribute__((ext_vector_type(4))) float;

#define MFMA16(a,b,c) __builtin_amdgcn_mfma_f32_16x16x32_bf16(a,b,c,0,0,0)

__device__ __forceinline__ short f2bf(float f){
  union { float f; unsigned u; } c; c.f = f;
  unsigned u = c.u;
  u += 0x7fffu + ((u >> 16) & 1u);   // RNE
  return (short)(u >> 16);
}

// stage 16 f32 -> 16 bf16 into LDS (dst 16B-aligned)
__device__ __forceinline__ void stage16f(short* dst, const float* __restrict__ src){
  floatv4 a = *(const floatv4*)(src + 0);
  floatv4 b = *(const floatv4*)(src + 4);
  floatv4 c = *(const floatv4*)(src + 8);
  floatv4 d = *(const floatv4*)(src + 12);
  short8 s0, s1;
  #pragma unroll
  for (int i = 0; i < 4; ++i){
    s0[i]   = f2bf(a[i]); s0[4+i] = f2bf(b[i]);
    s1[i]   = f2bf(c[i]); s1[4+i] = f2bf(d[i]);
  }
  *(short8*)(dst)     = s0;
  *(short8*)(dst + 8) = s1;
}

// stage 16 bf16 -> LDS
__device__ __forceinline__ void stage16b(short* dst, const short* __restrict__ src){
  *(short8*)(dst)     = *(const short8*)(src);
  *(short8*)(dst + 8) = *(const short8*)(src + 8);
}

// ---------------------------------------------------------------------------
// 1) Fused Q/K/V projection: q = (x@Wq^T + bq) * 1/64 ; k = x@Wk^T + bk ; v = ...
//    grid (512, 12), block 256. Tile 64x64, K-step 64.
// ---------------------------------------------------------------------------
__global__ __launch_bounds__(256) void proj_qkv(
    const float* __restrict__ x,
    const float* __restrict__ Wq, const float* __restrict__ bq,
    const float* __restrict__ Wk, const float* __restrict__ bk,
    const float* __restrict__ Wv, const float* __restrict__ bv,
    short* __restrict__ qo, short* __restrict__ ko, short* __restrict__ vo)
{
  __shared__ short xA[64][72];
  __shared__ short wB[3][64][72];
  const int m0 = blockIdx.x * 64;
  const int n0 = blockIdx.y * 64;
  const int t = threadIdx.x;
  const int lane = t & 63, wid = t >> 6;
  const int wr = (wid >> 1) * 32, wc = (wid & 1) * 32;
  const int srow = t >> 2, scb = (t & 3) * 16;
  const int arow = lane & 15, kcol0 = (lane >> 4) * 8;

  const float* Ws[3] = {Wq, Wk, Wv};

  f32x4 acc[3][2][2];
  #pragma unroll
  for (int p=0;p<3;p++)
    #pragma unroll
    for (int m=0;m<2;m++)
      #pragma unroll
      for (int n=0;n<2;n++)
        acc[p][m][n] = (f32x4){0.f,0.f,0.f,0.f};

  for (int kt = 0; kt < E_/64; ++kt){
    const int k0 = kt * 64;
    stage16f(&xA[srow][scb], x + (long)(m0 + srow) * E_ + k0 + scb);
    #pragma unroll
    for (int p=0;p<3;p++)
      stage16f(&wB[p][srow][scb], Ws[p] + (long)(n0 + srow) * E_ + k0 + scb);
    __syncthreads();
    #pragma unroll
    for (int ks=0; ks<2; ++ks){
      short8 af[2];
      #pragma unroll
      for (int m=0;m<2;m++)
        af[m] = *(const short8*)&xA[wr + m*16 + arow][ks*32 + kcol0];
      #pragma unroll
      for (int p=0;p<3;p++){
        #pragma unroll
        for (int n=0;n<2;n++){
          short8 bf = *(const short8*)&wB[p][wc + n*16 + arow][ks*32 + kcol0];
          #pragma unroll
          for (int m=0;m<2;m++)
            acc[p][m][n] = MFMA16(af[m], bf, acc[p][m][n]);
        }
      }
    }
    __syncthreads();
  }

  const float* bs[3] = {bq, bk, bv};
  short* outp[3] = {qo, ko, vo};
  const int col = lane & 15, rbase = (lane >> 4) * 4;
  #pragma unroll
  for (int p=0;p<3;p++){
    #pragma unroll
    for (int n=0;n<2;n++){
      const int gc = n0 + wc + n*16 + col;
      const float bias = bs[p][gc];
      #pragma unroll
      for (int m=0;m<2;m++){
        #pragma unroll
        for (int rg=0;rg<4;rg++){
          const int gm = m0 + wr + m*16 + rbase + rg;
          float v = acc[p][m][n][rg] + bias;
          if (p == 0) v *= 0.015625f;   // (D^-0.5)/sqrt(R) = (1/8)/8
          outp[p][(long)gm * E_ + gc] = f2bf(v);
        }
      }
    }
  }
}

// ---------------------------------------------------------------------------
// 2) Tied-row logits: S[h][i][j] = sum_r sum_d q[r,i,h,d]*k[r,j,h,d], diag=-1e9
//    grid (8 jt, 8 it, 12 h), block 256. Writes f32 into d_out attn region.
// ---------------------------------------------------------------------------
__global__ __launch_bounds__(256) void logits_k(
    const short* __restrict__ q, const short* __restrict__ k,
    float* __restrict__ Sout)
{
  __shared__ short qA[64][72];
  __shared__ short kB[64][72];
  const int jt = blockIdx.x, it = blockIdx.y, h = blockIdx.z;
  const int i0 = it*64, j0 = jt*64;
  const int t = threadIdx.x;
  const int lane = t & 63, wid = t >> 6;
  const int wr = (wid >> 1) * 32, wc = (wid & 1) * 32;
  const int srow = t >> 2, scb = (t & 3) * 16;
  const int arow = lane & 15, kcol0 = (lane >> 4) * 8;

  f32x4 acc[2][2];
  #pragma unroll
  for (int m=0;m<2;m++)
    #pragma unroll
    for (int n=0;n<2;n++)
      acc[m][n] = (f32x4){0.f,0.f,0.f,0.f};

  for (int r = 0; r < R_; ++r){
    stage16b(&qA[srow][scb], q + (long)(r*C_ + i0 + srow) * E_ + h*D_ + scb);
    stage16b(&kB[srow][scb], k + (long)(r*C_ + j0 + srow) * E_ + h*D_ + scb);
    __syncthreads();
    #pragma unroll
    for (int ks=0; ks<2; ++ks){
      short8 af[2], bf[2];
      #pragma unroll
      for (int m=0;m<2;m++)
        af[m] = *(const short8*)&qA[wr + m*16 + arow][ks*32 + kcol0];
      #pragma unroll
      for (int n=0;n<2;n++)
        bf[n] = *(const short8*)&kB[wc + n*16 + arow][ks*32 + kcol0];
      #pragma unroll
      for (int m=0;m<2;m++)
        #pragma unroll
        for (int n=0;n<2;n++)
          acc[m][n] = MFMA16(af[m], bf[n], acc[m][n]);
    }
    __syncthreads();
  }

  const int col = lane & 15, rbase = (lane >> 4) * 4;
  #pragma unroll
  for (int m=0;m<2;m++){
    #pragma unroll
    for (int n=0;n<2;n++){
      #pragma unroll
      for (int rg=0;rg<4;rg++){
        const int gi = i0 + wr + m*16 + rbase + rg;
        const int gj = j0 + wc + n*16 + col;
        float v = acc[m][n][rg];
        if (gi == gj) v = -1e9f;
        Sout[(long)h * C_ * C_ + (long)gi * C_ + gj] = v;
      }
    }
  }
}

// ---------------------------------------------------------------------------
// 3) Row softmax over 512; in-place f32 + bf16 copy. grid (6144), block 256.
// ---------------------------------------------------------------------------
__global__ __launch_bounds__(256) void softmax_k(
    float* __restrict__ S, short* __restrict__ Pbf)
{
  const int row = blockIdx.x;       // h*512 + i
  float* p = S + (long)row * C_;
  const int t = threadIdx.x, lane = t & 63, wid = t >> 6;
  __shared__ float red[4];

  float v0 = p[t], v1 = p[t + 256];
  float mx = fmaxf(v0, v1);
  #pragma unroll
  for (int m = 1; m < 64; m <<= 1) mx = fmaxf(mx, __shfl_xor(mx, m, 64));
  if (lane == 0) red[wid] = mx;
  __syncthreads();
  mx = fmaxf(fmaxf(red[0], red[1]), fmaxf(red[2], red[3]));
  __syncthreads();

  float e0 = __expf(v0 - mx), e1 = __expf(v1 - mx);
  float s = e0 + e1;
  #pragma unroll
  for (int m = 1; m < 64; m <<= 1) s += __shfl_xor(s, m, 64);
  if (lane == 0) red[wid] = s;
  __syncthreads();
  const float tot = red[0] + red[1] + red[2] + red[3];
  const float inv = 1.0f / tot;

  const float p0 = e0 * inv, p1 = e1 * inv;
  p[t] = p0; p[t + 256] = p1;
  Pbf[(long)row * C_ + t] = f2bf(p0);
  Pbf[(long)row * C_ + t + 256] = f2bf(p1);
}

// ---------------------------------------------------------------------------
// 4) V transpose: vt[((r*H+h)*64+d)][j] = v[(r*C+j)*E + h*64+d]
//    grid (12 h, 64 r), block 256.
// ---------------------------------------------------------------------------
__global__ __launch_bounds__(256) void vtrans_k(
    const short* __restrict__ v, short* __restrict__ vt)
{
  __shared__ short tile[64][72];
  const int h = blockIdx.x, r = blockIdx.y;
  const int t = threadIdx.x;
  const int srow = t >> 2, scb = (t & 3) * 16;

  for (int jc = 0; jc < 8; ++jc){
    stage16b(&tile[srow][scb], v + (long)(r*C_ + jc*64 + srow) * E_ + h*D_ + scb);
    __syncthreads();
    short tmp[16];
    #pragma unroll
    for (int i = 0; i < 16; ++i) tmp[i] = tile[scb + i][srow];
    short* dst = vt + (long)((r*H_ + h)*D_ + srow) * C_ + jc*64 + scb;
    *(short8*)(dst)     = *(short8*)&tmp[0];
    *(short8*)(dst + 8) = *(short8*)&tmp[8];
    __syncthreads();
  }
}

// ---------------------------------------------------------------------------
// 5) Context: ctx[r,i,h,d] = sum_j P[h,i,j] * v[r,j,h,d]  (vt layout NT GEMM)
//    grid (8 it, 12 h, 64 r), block 256.
// ---------------------------------------------------------------------------
__global__ __launch_bounds__(256) void ctx_k(
    const short* __restrict__ P, const short* __restrict__ vt,
    short* __restrict__ ctx)
{
  __shared__ short pA[64][72];
  __shared__ short vB[64][72];
  const int it = blockIdx.x, h = blockIdx.y, r = blockIdx.z;
  const int i0 = it * 64;
  const int t = threadIdx.x;
  const int lane = t & 63, wid = t >> 6;
  const int wr = (wid >> 1) * 32, wc = (wid & 1) * 32;
  const int srow = t >> 2, scb = (t & 3) * 16;
  const int arow = lane & 15, kcol0 = (lane >> 4) * 8;

  f32x4 acc[2][2];
  #pragma unroll
  for (int m=0;m<2;m++)
    #pragma unroll
    for (int n=0;n<2;n++)
      acc[m][n] = (f32x4){0.f,0.f,0.f,0.f};

  for (int jt = 0; jt < 8; ++jt){
    stage16b(&pA[srow][scb], P  + (long)(h*C_ + i0 + srow) * C_ + jt*64 + scb);
    stage16b(&vB[srow][scb], vt + (long)((r*H_ + h)*D_ + srow) * C_ + jt*64 + scb);
    __syncthreads();
    #pragma unroll
    for (int ks=0; ks<2; ++ks){
      short8 af[2], bf[2];
      #pragma unroll
      for (int m=0;m<2;m++)
        af[m] = *(const short8*)&pA[wr + m*16 + arow][ks*32 + kcol0];
      #pragma unroll
      for (int n=0;n<2;n++)
        bf[n] = *(const short8*)&vB[wc + n*16 + arow][ks*32 + kcol0];
      #pragma unroll
      for (int m=0;m<2;m++)
        #pragma unroll
        for (int n=0;n<2;n++)
          acc[m][n] = MFMA16(af[m], bf[n], acc[m][n]);
    }
    __syncthreads();
  }

  const int col = lane & 15, rbase = (lane >> 4) * 4;
  #pragma unroll
  for (int m=0;m<2;m++){
    #pragma unroll
    for (int n=0;n<2;n++){
      #pragma unroll
      for (int rg=0;rg<4;rg++){
        const int gi = i0 + wr + m*16 + rbase + rg;
        const int gd = wc + n*16 + col;
        ctx[(long)(r*C_ + gi) * E_ + h*D_ + gd] = f2bf(acc[m][n][rg]);
      }
    }
  }
}

// ---------------------------------------------------------------------------
// 6) Output projection: out = ctx @ Wo^T + bo (f32 out). grid (512,12), 256.
// ---------------------------------------------------------------------------
__global__ __launch_bounds__(256) void oproj_k(
    const short* __restrict__ ctx, const float* __restrict__ Wo,
    const float* __restrict__ bo, float* __restrict__ out)
{
  __shared__ short cA[64][72];
  __shared__ short wB[64][72];
  const int m0 = blockIdx.x * 64;
  const int n0 = blockIdx.y * 64;
  const int t = threadIdx.x;
  const int lane = t & 63, wid = t >> 6;
  const int wr = (wid >> 1) * 32, wc = (wid & 1) * 32;
  const int srow = t >> 2, scb = (t & 3) * 16;
  const int arow = lane & 15, kcol0 = (lane >> 4) * 8;

  f32x4 acc[2][2];
  #pragma unroll
  for (int m=0;m<2;m++)
    #pragma unroll
    for (int n=0;n<2;n++)
      acc[m][n] = (f32x4){0.f,0.f,0.f,0.f};

  for (int kt = 0; kt < E_/64; ++kt){
    const int k0 = kt * 64;
    stage16b(&cA[srow][scb], ctx + (long)(m0 + srow) * E_ + k0 + scb);
    stage16f(&wB[srow][scb], Wo + (long)(n0 + srow) * E_ + k0 + scb);
    __syncthreads();
    #pragma unroll
    for (int ks=0; ks<2; ++ks){
      short8 af[2], bf[2];
      #pragma unroll
      for (int m=0;m<2;m++)
        af[m] = *(const short8*)&cA[wr + m*16 + arow][ks*32 + kcol0];
      #pragma unroll
      for (int n=0;n<2;n++)
        bf[n] = *(const short8*)&wB[wc + n*16 + arow][ks*32 + kcol0];
      #pragma unroll
      for (int m=0;m<2;m++)
        #pragma unroll
        for (int n=0;n<2;n++)
          acc[m][n] = MFMA16(af[m], bf[n], acc[m][n]);
    }
    __syncthreads();
  }

  const int col = lane & 15, rbase = (lane >> 4) * 4;
  #pragma unroll
  for (int n=0;n<2;n++){
    const int gc = n0 + wc + n*16 + col;
    const float bias = bo[gc];
    #pragma unroll
    for (int m=0;m<2;m++){
      #pragma unroll
      for (int rg=0;rg<4;rg++){
        const int gm = m0 + wr + m*16 + rbase + rg;
        out[(long)gm * E_ + gc] = acc[m][n][rg] + bias;
      }
    }
  }
}

// ---------------------------------------------------------------------------
extern "C" void kernel_launch(void* const* d_in, const int* in_sizes, int n_in,
                              void* d_out, int out_size, void* d_ws, size_t ws_size,
                              hipStream_t stream)
{
  const float* x  = (const float*)d_in[0];
  // d_in[1] = network (unused by reference)
  const float* Wq = (const float*)d_in[2];
  const float* bq = (const float*)d_in[3];
  const float* Wk = (const float*)d_in[4];
  const float* bk = (const float*)d_in[5];
  const float* Wv = (const float*)d_in[6];
  const float* bv = (const float*)d_in[7];
  const float* Wo = (const float*)d_in[8];
  const float* bo = (const float*)d_in[9];
  const float* l  = (const float*)d_in[10];

  float* out   = (float*)d_out;                          // [32768][768]
  float* probs = out + (size_t)M_TOT * E_;               // [12][512][512] f32
  float* lout  = probs + (size_t)H_ * C_ * C_;           // [12]

  short* ws_s = (short*)d_ws;
  const size_t SLOT = (size_t)M_TOT * E_;                // 25,165,824 elems
  short* qb = ws_s;                                      // slot A: q bf16
  short* kb = ws_s + SLOT;                               // slot B: k bf16
  short* vb = ws_s + 2*SLOT;                             // slot C: v bf16
  short* pb = ws_s + 3*SLOT;                             // probs bf16 (6 MB)
  short* vtb  = qb;                                      // vt reuses q (dead after logits)
  short* ctxb = kb;                                      // ctx reuses k (dead after logits)

  hipMemcpyAsync(lout, l, 12 * sizeof(float), hipMemcpyDeviceToDevice, stream);

  proj_qkv<<<dim3(M_TOT/64, E_/64), 256, 0, stream>>>(x, Wq, bq, Wk, bk, Wv, bv, qb, kb, vb);
  logits_k<<<dim3(8, 8, H_), 256, 0, stream>>>(qb, kb, probs);
  softmax_k<<<dim3(H_ * C_), 256, 0, stream>>>(probs, pb);
  vtrans_k<<<dim3(H_, R_), 256, 0, stream>>>(vb, vtb);
  ctx_k<<<dim3(8, H_, R_), 256, 0, stream>>>(pb, vtb, ctxb);
  oproj_k<<<dim3(M_TOT/64, E_/64), 256, 0, stream>>>(ctxb, Wo, bo, out);
}

// Round 2
// 410.512 us; speedup vs baseline: 1.5938x; 1.5938x over previous
//
#include <hip/hip_runtime.h>
#include <stdint.h>

#define R_ 64
#define C_ 512
#define E_ 768
#define H_ 12
#define D_ 64
#define M_TOT (R_*C_)   // 32768

using short8  = __attribute__((ext_vector_type(8))) short;
using f32x4   = __attribute__((ext_vector_type(4))) float;
using floatv4 = __attribute__((ext_vector_type(4))) float;

#define MFMA16(a,b,c) __builtin_amdgcn_mfma_f32_16x16x32_bf16(a,b,c,0,0,0)

__device__ __forceinline__ short f2bf(float f){
  union { float f; unsigned u; } c; c.f = f;
  unsigned u = c.u;
  u += 0x7fffu + ((u >> 16) & 1u);   // RNE
  return (short)(u >> 16);
}

// async global->LDS, 16B per lane. LDS dest must be wave-uniform base; HW adds lane*16.
__device__ __forceinline__ void gload16(const void* g, void* lds){
  __builtin_amdgcn_global_load_lds(
      (const __attribute__((address_space(1))) void*)(uintptr_t)g,
      (__attribute__((address_space(3))) void*)(uint32_t)(uintptr_t)lds,
      16, 0, 0);
}

struct Lin {
  const short* p; int ld;
  __device__ __forceinline__ const short* at(int r, int c) const {
    return p + (long)r * ld + c;
  }
};
// oproj A operand: ctx stored as ctx_t[h][i][r*64+d]; m = r*512+i, k = h*64+d
struct CtxMap {
  const short* p;
  __device__ __forceinline__ const short* at(int m, int k) const {
    return p + ((long)((k >> 6) * 512 + (m & 511))) * 4096 + ((m >> 9) << 6) + (k & 63);
  }
};

// ---------------------------------------------------------------------------
// 128x128 tile, BK=64, 4 waves (2x2), each wave 64x64 = 4x4 frags of 16x16x32.
// global_load_lds direct staging, linear LDS dest + inverse-swizzled global
// source + swizzled ds_read (T2, rule #21). LDS row = 64 bf16 = 128 B;
// swizzle: 16B-group cg' = cg ^ (row&7).
// ---------------------------------------------------------------------------
template<class AT, class BT>
__device__ __forceinline__ void gemm_core128(
    const AT& A, const BT& B, int m0, int n0, int K,
    short* lA, short* lB, f32x4 (&acc)[4][4])
{
  const int t = threadIdx.x, l = t & 63, w = t >> 6;
  const int wr = (w >> 1) * 64, wc = (w & 1) * 64;
  const int lr = l >> 3;       // 0..7   sub-row within staging issue
  const int cg = l & 7;        // 0..7   16B group within 128B row
  const int fr = l & 15;       // fragment row
  const int fk = l >> 4;       // 0..3   k-subgroup

  for (int k0 = 0; k0 < K; k0 += 64){
    #pragma unroll
    for (int j = 0; j < 4; ++j){
      const int row = (w*4 + j)*8 + lr;          // 0..127
      const int sc  = ((cg ^ (row & 7)) << 3);   // inverse-swizzled source col
      gload16(A.at(m0 + row, k0 + sc), lA + (w*4 + j)*512);
      gload16(B.at(n0 + row, k0 + sc), lB + (w*4 + j)*512);
    }
    __syncthreads();   // compiler drains vmcnt(0) here -> LDS valid
    #pragma unroll
    for (int ks = 0; ks < 2; ++ks){
      short8 af[4], bf[4];
      #pragma unroll
      for (int m = 0; m < 4; ++m){
        const int r = wr + m*16 + fr;
        const int g = (ks*4 + fk) ^ (r & 7);
        af[m] = *(const short8*)((const char*)lA + r*128 + g*16);
      }
      #pragma unroll
      for (int n = 0; n < 4; ++n){
        const int r = wc + n*16 + fr;
        const int g = (ks*4 + fk) ^ (r & 7);
        bf[n] = *(const short8*)((const char*)lB + r*128 + g*16);
      }
      #pragma unroll
      for (int m = 0; m < 4; ++m)
        #pragma unroll
        for (int n = 0; n < 4; ++n)
          acc[m][n] = MFMA16(af[m], bf[n], acc[m][n]);
    }
    __syncthreads();
  }
}

#define ACC_INIT(acc) \
  _Pragma("unroll") for (int m_=0;m_<4;m_++) _Pragma("unroll") for (int n_=0;n_<4;n_++) \
    acc[m_][n_] = (f32x4){0.f,0.f,0.f,0.f};

// ---------------------------------------------------------------------------
// f32 -> bf16 conversion, 8 elems/thread, grid-stride.
// ---------------------------------------------------------------------------
__global__ __launch_bounds__(256) void cvt_k(
    const float* __restrict__ in, short* __restrict__ out, int n8, float scale)
{
  int i = blockIdx.x * blockDim.x + threadIdx.x;
  const int stride = gridDim.x * blockDim.x;
  for (; i < n8; i += stride){
    floatv4 a = *(const floatv4*)(in + (long)i*8);
    floatv4 b = *(const floatv4*)(in + (long)i*8 + 4);
    short8 s;
    #pragma unroll
    for (int j = 0; j < 4; ++j){ s[j] = f2bf(a[j]*scale); s[4+j] = f2bf(b[j]*scale); }
    *(short8*)(out + (long)i*8) = s;
  }
}

// ---------------------------------------------------------------------------
// Projection: out = xb @ Wb[which]^T + bias, written permuted as
// out[h][pos][r*64+d]. which: 0=q (W,b pre-scaled), 1=k, 2=v.
// grid (M/128, 768/128, nz), zbase selects which.
// ---------------------------------------------------------------------------
__global__ __launch_bounds__(256) void proj_k(
    const short* __restrict__ xb, const short* __restrict__ wb,
    const float* __restrict__ bq, const float* __restrict__ bk, const float* __restrict__ bv,
    short* __restrict__ outA, short* __restrict__ outB, int zbase)
{
  __shared__ short lA[128*64];
  __shared__ short lB[128*64];
  const int which = blockIdx.z + zbase;
  const int m0 = blockIdx.x * 128, n0 = blockIdx.y * 128;

  f32x4 acc[4][4]; ACC_INIT(acc);
  Lin A{xb, E_};
  Lin B{wb + (long)which * E_ * E_, E_};
  gemm_core128(A, B, m0, n0, E_, lA, lB, acc);

  const float* bias = (which == 0) ? bq : (which == 1 ? bk : bv);
  short* out = (which == 1) ? outB : outA;
  const float sc = (which == 0) ? 0.015625f : 1.0f;   // q: (xW+b)*s, W pre-scaled, scale b here

  const int t = threadIdx.x, l = t & 63, w = t >> 6;
  const int wr = (w >> 1) * 64, wc = (w & 1) * 64;
  #pragma unroll
  for (int n = 0; n < 4; ++n){
    const int gc = n0 + wc + n*16 + (l & 15);
    const float bb = bias[gc] * sc;
    const int h = gc >> 6, d = gc & 63;
    #pragma unroll
    for (int m = 0; m < 4; ++m){
      #pragma unroll
      for (int rg = 0; rg < 4; ++rg){
        const int gm = m0 + wr + m*16 + (l >> 4)*4 + rg;
        const int i = gm & 511, r = gm >> 9;
        out[((long)(h*512 + i))*4096 + r*64 + d] = f2bf(acc[m][n][rg] + bb);
      }
    }
  }
}

// ---------------------------------------------------------------------------
// Logits: per head, S = Q_h @ K_h^T over K=4096 (=R*D), diag = -1e9, f32 out.
// grid (4, 4, 12).
// ---------------------------------------------------------------------------
__global__ __launch_bounds__(256) void logits_k(
    const short* __restrict__ qt, const short* __restrict__ kt, float* __restrict__ S)
{
  __shared__ short lA[128*64];
  __shared__ short lB[128*64];
  const int h = blockIdx.z;
  const int m0 = blockIdx.x * 128, n0 = blockIdx.y * 128;

  f32x4 acc[4][4]; ACC_INIT(acc);
  Lin A{qt + (long)h * C_ * 4096, 4096};
  Lin B{kt + (long)h * C_ * 4096, 4096};
  gemm_core128(A, B, m0, n0, 4096, lA, lB, acc);

  const int t = threadIdx.x, l = t & 63, w = t >> 6;
  const int wr = (w >> 1) * 64, wc = (w & 1) * 64;
  float* Sh = S + (long)h * C_ * C_;
  #pragma unroll
  for (int m = 0; m < 4; ++m){
    #pragma unroll
    for (int n = 0; n < 4; ++n){
      #pragma unroll
      for (int rg = 0; rg < 4; ++rg){
        const int gi = m0 + wr + m*16 + (l >> 4)*4 + rg;
        const int gj = n0 + wc + n*16 + (l & 15);
        float v = acc[m][n][rg];
        if (gi == gj) v = -1e9f;
        Sh[(long)gi * C_ + gj] = v;
      }
    }
  }
}

// ---------------------------------------------------------------------------
// Row softmax over 512; f32 in-place + bf16 copy. grid (6144), block 256.
// ---------------------------------------------------------------------------
__global__ __launch_bounds__(256) void softmax_k(
    float* __restrict__ S, short* __restrict__ Pbf)
{
  const int row = blockIdx.x;       // h*512 + i
  float* p = S + (long)row * C_;
  const int t = threadIdx.x, lane = t & 63, wid = t >> 6;
  __shared__ float red[4];

  float v0 = p[t], v1 = p[t + 256];
  float mx = fmaxf(v0, v1);
  #pragma unroll
  for (int m = 1; m < 64; m <<= 1) mx = fmaxf(mx, __shfl_xor(mx, m, 64));
  if (lane == 0) red[wid] = mx;
  __syncthreads();
  mx = fmaxf(fmaxf(red[0], red[1]), fmaxf(red[2], red[3]));
  __syncthreads();

  float e0 = __expf(v0 - mx), e1 = __expf(v1 - mx);
  float s = e0 + e1;
  #pragma unroll
  for (int m = 1; m < 64; m <<= 1) s += __shfl_xor(s, m, 64);
  if (lane == 0) red[wid] = s;
  __syncthreads();
  const float tot = red[0] + red[1] + red[2] + red[3];
  const float inv = 1.0f / tot;

  const float p0 = e0 * inv, p1 = e1 * inv;
  p[t] = p0; p[t + 256] = p1;
  Pbf[(long)row * C_ + t] = f2bf(p0);
  Pbf[(long)row * C_ + t + 256] = f2bf(p1);
}

// ---------------------------------------------------------------------------
// v transpose per head: vt[h][j][rd] (ld 4096) -> vtt[h][rd][j] (ld 512).
// grid (8 jt, 64 rdt, 12 h), one 64x64 bf16 tile per block.
// ---------------------------------------------------------------------------
__global__ __launch_bounds__(256) void vtrans_k(
    const short* __restrict__ vt, short* __restrict__ vtt)
{
  __shared__ short tile[64][72];
  const int jt = blockIdx.x, rt = blockIdx.y, h = blockIdx.z;
  const int t = threadIdx.x, srow = t >> 2, scb = (t & 3) * 16;

  const short* src = vt + (long)h*C_*4096 + (long)(jt*64 + srow)*4096 + rt*64 + scb;
  *(short8*)&tile[srow][scb]     = *(const short8*)(src);
  *(short8*)&tile[srow][scb + 8] = *(const short8*)(src + 8);
  __syncthreads();
  short tmp[16];
  #pragma unroll
  for (int i = 0; i < 16; ++i) tmp[i] = tile[scb + i][srow];
  short* dst = vtt + (long)h*4096*C_ + (long)(rt*64 + srow)*C_ + jt*64 + scb;
  *(short8*)(dst)     = *(short8*)&tmp[0];
  *(short8*)(dst + 8) = *(short8*)&tmp[8];
}

// ---------------------------------------------------------------------------
// Context: per head, ctx_t[h][i][rd] = P_h[i][j] @ Vtt_h[rd][j]^T (NT, K=512).
// grid (4, 32, 12), bf16 out.
// ---------------------------------------------------------------------------
__global__ __launch_bounds__(256) void ctx_k(
    const short* __restrict__ pb, const short* __restrict__ vtt, short* __restrict__ ctx_t)
{
  __shared__ short lA[128*64];
  __shared__ short lB[128*64];
  const int h = blockIdx.z;
  const int m0 = blockIdx.x * 128, n0 = blockIdx.y * 128;

  f32x4 acc[4][4]; ACC_INIT(acc);
  Lin A{pb + (long)h * C_ * C_, C_};
  Lin B{vtt + (long)h * 4096 * C_, C_};
  gemm_core128(A, B, m0, n0, C_, lA, lB, acc);

  const int t = threadIdx.x, l = t & 63, w = t >> 6;
  const int wr = (w >> 1) * 64, wc = (w & 1) * 64;
  short* outh = ctx_t + (long)h * C_ * 4096;
  #pragma unroll
  for (int m = 0; m < 4; ++m){
    #pragma unroll
    for (int n = 0; n < 4; ++n){
      #pragma unroll
      for (int rg = 0; rg < 4; ++rg){
        const int gi = m0 + wr + m*16 + (l >> 4)*4 + rg;
        const int gn = n0 + wc + n*16 + (l & 15);
        outh[(long)gi * 4096 + gn] = f2bf(acc[m][n][rg]);
      }
    }
  }
}

// ---------------------------------------------------------------------------
// Output projection: out = ctx @ Wo^T + bo, f32 out, A via CtxMap.
// grid (256, 6).
// ---------------------------------------------------------------------------
__global__ __launch_bounds__(256) void oproj_k(
    const short* __restrict__ ctx_t, const short* __restrict__ wo,
    const float* __restrict__ bo, float* __restrict__ out)
{
  __shared__ short lA[128*64];
  __shared__ short lB[128*64];
  const int m0 = blockIdx.x * 128, n0 = blockIdx.y * 128;

  f32x4 acc[4][4]; ACC_INIT(acc);
  CtxMap A{ctx_t};
  Lin B{wo, E_};
  gemm_core128(A, B, m0, n0, E_, lA, lB, acc);

  const int t = threadIdx.x, l = t & 63, w = t >> 6;
  const int wr = (w >> 1) * 64, wc = (w & 1) * 64;
  #pragma unroll
  for (int n = 0; n < 4; ++n){
    const int gc = n0 + wc + n*16 + (l & 15);
    const float bb = bo[gc];
    #pragma unroll
    for (int m = 0; m < 4; ++m){
      #pragma unroll
      for (int rg = 0; rg < 4; ++rg){
        const int gm = m0 + wr + m*16 + (l >> 4)*4 + rg;
        out[(long)gm * E_ + gc] = acc[m][n][rg] + bb;
      }
    }
  }
}

// ---------------------------------------------------------------------------
extern "C" void kernel_launch(void* const* d_in, const int* in_sizes, int n_in,
                              void* d_out, int out_size, void* d_ws, size_t ws_size,
                              hipStream_t stream)
{
  const float* x  = (const float*)d_in[0];
  const float* Wq = (const float*)d_in[2];
  const float* bq = (const float*)d_in[3];
  const float* Wk = (const float*)d_in[4];
  const float* bk = (const float*)d_in[5];
  const float* Wv = (const float*)d_in[6];
  const float* bv = (const float*)d_in[7];
  const float* Wo = (const float*)d_in[8];
  const float* bo = (const float*)d_in[9];
  const float* l  = (const float*)d_in[10];

  float* out   = (float*)d_out;                          // [32768][768]
  float* probs = out + (size_t)M_TOT * E_;               // [12][512][512] f32
  float* lout  = probs + (size_t)H_ * C_ * C_;           // [12]

  short* ws_s = (short*)d_ws;
  const size_t SLOT = (size_t)M_TOT * E_;                // 25,165,824 elems
  short* s0 = ws_s;                // xb (cvt..proj_v), then pb (softmax..ctx)
  short* s1 = ws_s + SLOT;         // qt (..logits), vt (proj_v..vtrans), ctx_t (ctx..oproj)
  short* s2 = ws_s + 2*SLOT;       // kt (..logits), vtt (vtrans..ctx)
  short* wb = ws_s + 3*SLOT;       // 4 x 589824 bf16 weights

  hipMemcpyAsync(lout, l, H_ * sizeof(float), hipMemcpyDeviceToDevice, stream);

  // one-time bf16 conversions (Wq pre-scaled by (D^-0.5)/sqrt(R) = 1/64)
  cvt_k<<<2048, 256, 0, stream>>>(x,  s0, (int)(SLOT/8), 1.0f);
  cvt_k<<<288,  256, 0, stream>>>(Wq, wb + 0*589824, 73728, 0.015625f);
  cvt_k<<<288,  256, 0, stream>>>(Wk, wb + 1*589824, 73728, 1.0f);
  cvt_k<<<288,  256, 0, stream>>>(Wv, wb + 2*589824, 73728, 1.0f);
  cvt_k<<<288,  256, 0, stream>>>(Wo, wb + 3*589824, 73728, 1.0f);

  // q,k projections (permuted layout), then logits while vt slot still free
  proj_k<<<dim3(M_TOT/128, E_/128, 2), 256, 0, stream>>>(s0, wb, bq, bk, bv, s1, s2, 0);
  logits_k<<<dim3(4, 4, H_), 256, 0, stream>>>(s1, s2, probs);
  // v projection (overwrites qt slot), softmax (pb overwrites xb slot)
  proj_k<<<dim3(M_TOT/128, E_/128, 1), 256, 0, stream>>>(s0, wb, bq, bk, bv, s1, s2, 2);
  softmax_k<<<dim3(H_ * C_), 256, 0, stream>>>(probs, s0);
  vtrans_k<<<dim3(8, 64, H_), 256, 0, stream>>>(s1, s2);
  ctx_k<<<dim3(4, 32, H_), 256, 0, stream>>>(s0, s2, s1);
  oproj_k<<<dim3(M_TOT/128, E_/128), 256, 0, stream>>>(s1, wb + 3*589824, bo, out);
}

// Round 3
// 350.645 us; speedup vs baseline: 1.8659x; 1.1707x over previous
//
#include <hip/hip_runtime.h>
#include <stdint.h>

#define R_ 64
#define C_ 512
#define E_ 768
#define H_ 12
#define D_ 64
#define M_TOT (R_*C_)   // 32768

using short8  = __attribute__((ext_vector_type(8))) short;
using f32x4   = __attribute__((ext_vector_type(4))) float;
using floatv4 = __attribute__((ext_vector_type(4))) float;

#define MFMA16(a,b,c) __builtin_amdgcn_mfma_f32_16x16x32_bf16(a,b,c,0,0,0)

__device__ __forceinline__ short f2bf(float f){
  union { float f; unsigned u; } c; c.f = f;
  unsigned u = c.u;
  u += 0x7fffu + ((u >> 16) & 1u);   // RNE
  return (short)(u >> 16);
}

// async global->LDS, 16B per lane. LDS dest is wave-uniform base; HW adds lane*16.
__device__ __forceinline__ void gload16(const void* g, void* lds){
  __builtin_amdgcn_global_load_lds(
      (const __attribute__((address_space(1))) void*)(uintptr_t)g,
      (__attribute__((address_space(3))) void*)(uint32_t)(uintptr_t)lds,
      16, 0, 0);
}

struct Lin {
  const short* p; int ld;
  __device__ __forceinline__ const short* at(int r, int c) const {
    return p + (long)r * ld + c;
  }
};
// oproj A operand: ctx stored as ctx_t[h][i][r*64+d]; m = r*512+i, k = h*64+d
struct CtxMap {
  const short* p;
  __device__ __forceinline__ const short* at(int m, int k) const {
    return p + ((long)((k >> 6) * 512 + (m & 511))) * 4096 + ((m >> 9) << 6) + (k & 63);
  }
};

// ---------------------------------------------------------------------------
// Deep-pipelined GEMM core. BM=256, BN=128, BK=64. 512 threads = 8 waves
// (4M x 2N), per-wave 64x64 output = 4x4 frags of 16x16x32.
// LDS: A 3 bufs x 32KB at smem + buf*16384 (shorts), B 3 bufs x 16KB at
// smem + 49152 + buf*8192. Stage K-tile t+2 while computing t; counted
// s_waitcnt vmcnt(6) (never 0 until tail). XOR-swizzle: 16B-group
// g' = g ^ (row&7), inverse-swizzled global source + linear LDS dest (#21).
// Race-freedom: buf[(t+2)%3] was last ds_read at iter t-1, whose reads are
// drained (lgkmcnt before MFMA) before the iter-(t-1) end barrier; stages for
// it are issued only after that barrier. Consumption of tile t+1 at iter t+1
// is gated by vmcnt(6) at iter t end (drains t+1's 6 loads) + barrier.
// ---------------------------------------------------------------------------
template<class AT, class BT>
__device__ __forceinline__ void gemm_core(
    const AT& A, const BT& B, int m0, int n0, int K,
    short* smem, f32x4 (&acc)[4][4])
{
  const int t = threadIdx.x, l = t & 63, w = t >> 6;
  const int wm = w >> 1, wn = w & 1;
  const int g_row8 = t >> 3;     // 0..63: row within a 64-row stage unit
  const int cg = t & 7;          // 16B group within 128B row

  auto stage = [&](int kt, int buf){
    const int k0 = kt * 64;
    short* dA = smem + buf * 16384;
    short* dB = smem + 49152 + buf * 8192;
    #pragma unroll
    for (int u = 0; u < 4; ++u){
      const int row = u*64 + g_row8;
      const int sc  = ((cg ^ (row & 7)) << 3);
      gload16(A.at(m0 + row, k0 + sc), dA + u*4096 + w*512);
    }
    #pragma unroll
    for (int u = 0; u < 2; ++u){
      const int row = u*64 + g_row8;
      const int sc  = ((cg ^ (row & 7)) << 3);
      gload16(B.at(n0 + row, k0 + sc), dB + u*4096 + w*512);
    }
  };

  const int NT = K >> 6;
  stage(0, 0);
  stage(1, 1);
  asm volatile("s_waitcnt vmcnt(6)" ::: "memory");   // tile 0 landed
  __builtin_amdgcn_s_barrier();
  asm volatile("" ::: "memory");

  int cur = 0;
  for (int kt = 0; kt < NT; ++kt){
    const int tgt = (cur == 0) ? 2 : cur - 1;        // (kt+2) % 3
    if (kt + 2 < NT) stage(kt + 2, tgt);

    const short* cA = smem + cur * 16384;
    const short* cB = smem + 49152 + cur * 8192;
    #pragma unroll
    for (int ks = 0; ks < 2; ++ks){
      short8 af[4], bf[4];
      #pragma unroll
      for (int m = 0; m < 4; ++m){
        const int r = wm*64 + m*16 + (l & 15);
        const int g = (ks*4 + (l >> 4)) ^ (r & 7);
        af[m] = *(const short8*)((const char*)cA + r*128 + g*16);
      }
      #pragma unroll
      for (int n = 0; n < 4; ++n){
        const int r = wn*64 + n*16 + (l & 15);
        const int g = (ks*4 + (l >> 4)) ^ (r & 7);
        bf[n] = *(const short8*)((const char*)cB + r*128 + g*16);
      }
      __builtin_amdgcn_s_setprio(1);
      #pragma unroll
      for (int m = 0; m < 4; ++m)
        #pragma unroll
        for (int n = 0; n < 4; ++n)
          acc[m][n] = MFMA16(af[m], bf[n], acc[m][n]);
      __builtin_amdgcn_s_setprio(0);
    }

    if (kt + 2 < NT) asm volatile("s_waitcnt vmcnt(6)" ::: "memory");
    else             asm volatile("s_waitcnt vmcnt(0)" ::: "memory");
    __builtin_amdgcn_s_barrier();
    asm volatile("" ::: "memory");
    cur = (cur == 2) ? 0 : cur + 1;
  }
}

#define ACC_INIT(acc) \
  _Pragma("unroll") for (int m_=0;m_<4;m_++) _Pragma("unroll") for (int n_=0;n_<4;n_++) \
    acc[m_][n_] = (f32x4){0.f,0.f,0.f,0.f};

// ---------------------------------------------------------------------------
// f32 -> bf16, 8 elems/thread, grid-stride.
// ---------------------------------------------------------------------------
__global__ __launch_bounds__(256) void cvt_k(
    const float* __restrict__ in, short* __restrict__ out, int n8, float scale)
{
  int i = blockIdx.x * blockDim.x + threadIdx.x;
  const int stride = gridDim.x * blockDim.x;
  for (; i < n8; i += stride){
    floatv4 a = *(const floatv4*)(in + (long)i*8);
    floatv4 b = *(const floatv4*)(in + (long)i*8 + 4);
    short8 s;
    #pragma unroll
    for (int j = 0; j < 4; ++j){ s[j] = f2bf(a[j]*scale); s[4+j] = f2bf(b[j]*scale); }
    *(short8*)(out + (long)i*8) = s;
  }
}

// all 4 weight matrices in one launch; Wq (region 0) pre-scaled by 1/64.
__global__ __launch_bounds__(256) void cvt_w_k(
    const float* __restrict__ Wq, const float* __restrict__ Wk,
    const float* __restrict__ Wv, const float* __restrict__ Wo,
    short* __restrict__ out)
{
  const int i = blockIdx.x * blockDim.x + threadIdx.x;   // 0..294911
  const int wsel = i / 73728, j = i - wsel * 73728;
  const float* src = (wsel == 0) ? Wq : (wsel == 1) ? Wk : (wsel == 2) ? Wv : Wo;
  const float scale = (wsel == 0) ? 0.015625f : 1.0f;
  floatv4 a = *(const floatv4*)(src + (long)j*8);
  floatv4 b = *(const floatv4*)(src + (long)j*8 + 4);
  short8 s;
  #pragma unroll
  for (int q = 0; q < 4; ++q){ s[q] = f2bf(a[q]*scale); s[4+q] = f2bf(b[q]*scale); }
  *(short8*)(out + (long)i*8) = s;
}

// ---------------------------------------------------------------------------
// Projection: out = xb @ W[which]^T + bias, written permuted as
// out[h][pos][r*64+d]. which: 0=q (pre-scaled), 1=k, 2=v. grid (128,6,nz).
// ---------------------------------------------------------------------------
__global__ __launch_bounds__(512, 2) void proj_k(
    const short* __restrict__ xb, const short* __restrict__ wb,
    const float* __restrict__ bq, const float* __restrict__ bk, const float* __restrict__ bv,
    short* __restrict__ outA, short* __restrict__ outB, int zbase)
{
  __shared__ short smem[73728];
  const int which = blockIdx.z + zbase;
  const int m0 = blockIdx.x * 256, n0 = blockIdx.y * 128;

  f32x4 acc[4][4]; ACC_INIT(acc);
  Lin A{xb, E_};
  Lin B{wb + (long)which * E_ * E_, E_};
  gemm_core(A, B, m0, n0, E_, smem, acc);

  const float* bias = (which == 0) ? bq : (which == 1 ? bk : bv);
  short* out = (which == 1) ? outB : outA;
  const float sc = (which == 0) ? 0.015625f : 1.0f;

  const int t = threadIdx.x, l = t & 63, w = t >> 6;
  const int wr = (w >> 1) * 64, wc = (w & 1) * 64;
  #pragma unroll
  for (int n = 0; n < 4; ++n){
    const int gc = n0 + wc + n*16 + (l & 15);
    const float bb = bias[gc] * sc;
    const int h = gc >> 6, d = gc & 63;
    #pragma unroll
    for (int m = 0; m < 4; ++m){
      #pragma unroll
      for (int rg = 0; rg < 4; ++rg){
        const int gm = m0 + wr + m*16 + (l >> 4)*4 + rg;
        const int i = gm & 511, r = gm >> 9;
        out[((long)(h*512 + i))*4096 + r*64 + d] = f2bf(acc[m][n][rg] + bb);
      }
    }
  }
}

// ---------------------------------------------------------------------------
// Logits split-K: slice s covers K in [s*1024, (s+1)*1024). grid (2,4,48),
// z = h*4 + s. Partial f32 tiles: s=0 -> probs region, s>0 -> out-region
// scratch (overwritten later by oproj). No diag mask here (done in softmax).
// ---------------------------------------------------------------------------
__global__ __launch_bounds__(512, 2) void logits_k(
    const short* __restrict__ qt, const short* __restrict__ kt,
    float* __restrict__ probs, float* __restrict__ scratch)
{
  __shared__ short smem[73728];
  const int h = blockIdx.z >> 2, s = blockIdx.z & 3;
  const int m0 = blockIdx.x * 256, n0 = blockIdx.y * 128;

  f32x4 acc[4][4]; ACC_INIT(acc);
  Lin A{qt + (long)h * C_ * 4096 + s*1024, 4096};
  Lin B{kt + (long)h * C_ * 4096 + s*1024, 4096};
  gemm_core(A, B, m0, n0, 1024, smem, acc);

  float* base = (s == 0) ? probs : scratch + (long)(s-1) * H_ * C_ * C_;
  float* Sh = base + (long)h * C_ * C_;
  const int t = threadIdx.x, l = t & 63, w = t >> 6;
  const int wr = (w >> 1) * 64, wc = (w & 1) * 64;
  #pragma unroll
  for (int m = 0; m < 4; ++m){
    #pragma unroll
    for (int n = 0; n < 4; ++n){
      #pragma unroll
      for (int rg = 0; rg < 4; ++rg){
        const int gi = m0 + wr + m*16 + (l >> 4)*4 + rg;
        const int gj = n0 + wc + n*16 + (l & 15);
        Sh[(long)gi * C_ + gj] = acc[m][n][rg];
      }
    }
  }
}

// ---------------------------------------------------------------------------
// softmax over 512 cols: sum 4 partials, mask diag, softmax.
// Writes f32 probs in place of partial0 + bf16 copy. grid (6144), block 256.
// ---------------------------------------------------------------------------
__global__ __launch_bounds__(256) void softmax4_k(
    float* __restrict__ S0, const float* __restrict__ S1, short* __restrict__ Pbf)
{
  const int row = blockIdx.x;       // h*512 + i
  const int i = row & 511;
  const long base = (long)row * C_;
  const long HCC = (long)H_ * C_ * C_;
  const int t = threadIdx.x, lane = t & 63, wid = t >> 6;
  __shared__ float red[4];

  float v0 = S0[base + t]       + S1[base + t]       + S1[base + t + HCC]       + S1[base + t + 2*HCC];
  float v1 = S0[base + t + 256] + S1[base + t + 256] + S1[base + t + 256 + HCC] + S1[base + t + 256 + 2*HCC];
  if (t == i)       v0 = -1e9f;
  if (t + 256 == i) v1 = -1e9f;

  float mx = fmaxf(v0, v1);
  #pragma unroll
  for (int m = 1; m < 64; m <<= 1) mx = fmaxf(mx, __shfl_xor(mx, m, 64));
  if (lane == 0) red[wid] = mx;
  __syncthreads();
  mx = fmaxf(fmaxf(red[0], red[1]), fmaxf(red[2], red[3]));
  __syncthreads();

  float e0 = __expf(v0 - mx), e1 = __expf(v1 - mx);
  float ssum = e0 + e1;
  #pragma unroll
  for (int m = 1; m < 64; m <<= 1) ssum += __shfl_xor(ssum, m, 64);
  if (lane == 0) red[wid] = ssum;
  __syncthreads();
  const float inv = 1.0f / (red[0] + red[1] + red[2] + red[3]);

  const float p0 = e0 * inv, p1 = e1 * inv;
  S0[base + t] = p0; S0[base + t + 256] = p1;
  Pbf[base + t] = f2bf(p0);
  Pbf[base + t + 256] = f2bf(p1);
}

// ---------------------------------------------------------------------------
// v transpose per head: vt[h][j][rd] (ld 4096) -> vtt[h][rd][j] (ld 512).
// grid (8 jt, 64 rdt, 12 h).
// ---------------------------------------------------------------------------
__global__ __launch_bounds__(256) void vtrans_k(
    const short* __restrict__ vt, short* __restrict__ vtt)
{
  __shared__ short tile[64][72];
  const int jt = blockIdx.x, rt = blockIdx.y, h = blockIdx.z;
  const int t = threadIdx.x, srow = t >> 2, scb = (t & 3) * 16;

  const short* src = vt + (long)h*C_*4096 + (long)(jt*64 + srow)*4096 + rt*64 + scb;
  *(short8*)&tile[srow][scb]     = *(const short8*)(src);
  *(short8*)&tile[srow][scb + 8] = *(const short8*)(src + 8);
  __syncthreads();
  short tmp[16];
  #pragma unroll
  for (int i = 0; i < 16; ++i) tmp[i] = tile[scb + i][srow];
  short* dst = vtt + (long)h*4096*C_ + (long)(rt*64 + srow)*C_ + jt*64 + scb;
  *(short8*)(dst)     = *(short8*)&tmp[0];
  *(short8*)(dst + 8) = *(short8*)&tmp[8];
}

// ---------------------------------------------------------------------------
// Context: per head, ctx_t[h][i][rd] = P_h[i][:] @ Vtt_h[rd][:]^T (NT, K=512).
// grid (2, 32, 12), bf16 out.
// ---------------------------------------------------------------------------
__global__ __launch_bounds__(512, 2) void ctx_k(
    const short* __restrict__ pb, const short* __restrict__ vtt, short* __restrict__ ctx_t)
{
  __shared__ short smem[73728];
  const int h = blockIdx.z;
  const int m0 = blockIdx.x * 256, n0 = blockIdx.y * 128;

  f32x4 acc[4][4]; ACC_INIT(acc);
  Lin A{pb + (long)h * C_ * C_, C_};
  Lin B{vtt + (long)h * 4096 * C_, C_};
  gemm_core(A, B, m0, n0, C_, smem, acc);

  const int t = threadIdx.x, l = t & 63, w = t >> 6;
  const int wr = (w >> 1) * 64, wc = (w & 1) * 64;
  short* outh = ctx_t + (long)h * C_ * 4096;
  #pragma unroll
  for (int m = 0; m < 4; ++m){
    #pragma unroll
    for (int n = 0; n < 4; ++n){
      #pragma unroll
      for (int rg = 0; rg < 4; ++rg){
        const int gi = m0 + wr + m*16 + (l >> 4)*4 + rg;
        const int gn = n0 + wc + n*16 + (l & 15);
        outh[(long)gi * 4096 + gn] = f2bf(acc[m][n][rg]);
      }
    }
  }
}

// ---------------------------------------------------------------------------
// Output projection: out = ctx @ Wo^T + bo, f32 out. grid (128, 6).
// ---------------------------------------------------------------------------
__global__ __launch_bounds__(512, 2) void oproj_k(
    const short* __restrict__ ctx_t, const short* __restrict__ wo,
    const float* __restrict__ bo, float* __restrict__ out)
{
  __shared__ short smem[73728];
  const int m0 = blockIdx.x * 256, n0 = blockIdx.y * 128;

  f32x4 acc[4][4]; ACC_INIT(acc);
  CtxMap A{ctx_t};
  Lin B{wo, E_};
  gemm_core(A, B, m0, n0, E_, smem, acc);

  const int t = threadIdx.x, l = t & 63, w = t >> 6;
  const int wr = (w >> 1) * 64, wc = (w & 1) * 64;
  #pragma unroll
  for (int n = 0; n < 4; ++n){
    const int gc = n0 + wc + n*16 + (l & 15);
    const float bb = bo[gc];
    #pragma unroll
    for (int m = 0; m < 4; ++m){
      #pragma unroll
      for (int rg = 0; rg < 4; ++rg){
        const int gm = m0 + wr + m*16 + (l >> 4)*4 + rg;
        out[(long)gm * E_ + gc] = acc[m][n][rg] + bb;
      }
    }
  }
}

// ---------------------------------------------------------------------------
extern "C" void kernel_launch(void* const* d_in, const int* in_sizes, int n_in,
                              void* d_out, int out_size, void* d_ws, size_t ws_size,
                              hipStream_t stream)
{
  const float* x  = (const float*)d_in[0];
  const float* Wq = (const float*)d_in[2];
  const float* bq = (const float*)d_in[3];
  const float* Wk = (const float*)d_in[4];
  const float* bk = (const float*)d_in[5];
  const float* Wv = (const float*)d_in[6];
  const float* bv = (const float*)d_in[7];
  const float* Wo = (const float*)d_in[8];
  const float* bo = (const float*)d_in[9];
  const float* l  = (const float*)d_in[10];

  float* out   = (float*)d_out;                          // [32768][768]
  float* probs = out + (size_t)M_TOT * E_;               // [12][512][512] f32
  float* lout  = probs + (size_t)H_ * C_ * C_;           // [12]

  short* ws_s = (short*)d_ws;
  const size_t SLOT = (size_t)M_TOT * E_;                // 25,165,824 elems
  short* s0 = ws_s;                // xb (cvt..proj_v), vtt (vtrans..ctx)
  short* s1 = ws_s + SLOT;         // qt (..logits), vt (proj_v..vtrans), ctx_t (ctx..oproj)
  short* s2 = ws_s + 2*SLOT;       // kt (..logits), pb (softmax..ctx)
  short* wb = ws_s + 3*SLOT;       // 4 x 589824 bf16 weights

  hipMemcpyAsync(lout, l, H_ * sizeof(float), hipMemcpyDeviceToDevice, stream);

  cvt_k<<<2048, 256, 0, stream>>>(x, s0, (int)(SLOT/8), 1.0f);
  cvt_w_k<<<1152, 256, 0, stream>>>(Wq, Wk, Wv, Wo, wb);

  // q,k projections -> logits (split-K partials into d_out scratch)
  proj_k<<<dim3(128, 6, 2), 512, 0, stream>>>(s0, wb, bq, bk, bv, s1, s2, 0);
  logits_k<<<dim3(2, 4, 48), 512, 0, stream>>>(s1, s2, probs, out);
  // v projection (overwrites qt), softmax (pb overwrites kt)
  proj_k<<<dim3(128, 6, 1), 512, 0, stream>>>(s0, wb, bq, bk, bv, s1, s2, 2);
  softmax4_k<<<dim3(H_ * C_), 256, 0, stream>>>(probs, out, s2);
  vtrans_k<<<dim3(8, 64, H_), 256, 0, stream>>>(s1, s0);
  ctx_k<<<dim3(2, 32, H_), 512, 0, stream>>>(s2, s0, s1);
  oproj_k<<<dim3(128, 6), 512, 0, stream>>>(s1, wb + 3*589824, bo, out);
}

// Round 4
// 336.035 us; speedup vs baseline: 1.9470x; 1.0435x over previous
//
#include <hip/hip_runtime.h>
#include <stdint.h>

#define R_ 64
#define C_ 512
#define E_ 768
#define H_ 12
#define D_ 64
#define M_TOT (R_*C_)   // 32768

using short8  = __attribute__((ext_vector_type(8))) short;
using f32x4   = __attribute__((ext_vector_type(4))) float;
using floatv4 = __attribute__((ext_vector_type(4))) float;

#define MFMA16(a,b,c) __builtin_amdgcn_mfma_f32_16x16x32_bf16(a,b,c,0,0,0)

__device__ __forceinline__ short f2bf(float f){
  union { float f; unsigned u; } c; c.f = f;
  unsigned u = c.u;
  u += 0x7fffu + ((u >> 16) & 1u);   // RNE
  return (short)(u >> 16);
}

// async global->LDS, 16B per lane. LDS dest is wave-uniform base; HW adds lane*16.
__device__ __forceinline__ void gload16(const void* g, void* lds){
  __builtin_amdgcn_global_load_lds(
      (const __attribute__((address_space(1))) void*)(uintptr_t)g,
      (__attribute__((address_space(3))) void*)(uint32_t)(uintptr_t)lds,
      16, 0, 0);
}

struct Lin {
  const short* p; int ld;
  __device__ __forceinline__ const short* at(int r, int c) const {
    return p + (long)r * ld + c;
  }
};
// oproj A operand: ctx stored as ctx_t[h][i][r*64+d]; m = r*512+i, k = h*64+d
struct CtxMap {
  const short* p;
  __device__ __forceinline__ const short* at(int m, int k) const {
    return p + ((long)((k >> 6) * 512 + (m & 511))) * 4096 + ((m >> 9) << 6) + (k & 63);
  }
};

// ---------------------------------------------------------------------------
// 4-phase-per-K-tile deep-pipelined GEMM core (m201-style schedule adapted).
// BM=256, BN=128, BK=64. 512 threads = 8 waves (4M x 2N), wave tile 64x64 =
// 4x4 frags of 16x16x32. LDS: A 3 bufs x 32KB (smem + buf*16384 shorts),
// B 3 bufs x 16KB (smem + 49152 + buf*8192). Stage K-tile t+2 spread across
// phases 0-2 of tile t (2 gloads each); counted s_waitcnt vmcnt(6) only at
// K-tile boundary. XOR-swizzle: LDS 16B-group g holds global group g^(row&7);
// reads apply the same XOR (both-sides, rule #21).
// Phase p: {ds_read quadrant frags | 2 gloads} BAR schedbar prio 8xMFMA prio BAR.
// Quadrants: p0 m01xn01, p1 m01xn23, p2 m23xn23, p3 m23xn01 (bf01 stay live).
// Race-freedom identical to prior round: slot (t+2)%3 was last read at tile
// t-1 whose reads complete before its trailing barrier; stages for it are
// issued only after that barrier. Consumption of tile t+1 gated by vmcnt(6).
// ---------------------------------------------------------------------------
template<class AT, class BT>
__device__ __forceinline__ void gemm_core(
    const AT& A, const BT& B, int m0, int n0, int K,
    short* smem, f32x4 (&acc)[4][4])
{
  const int t = threadIdx.x, l = t & 63, w = t >> 6;
  const int wm = w >> 1, wn = w & 1;
  const int g_row8 = t >> 3;     // 0..63: row within a 64-row stage unit
  const int cg = t & 7;          // 16B group within 128B row

  auto stageA = [&](int kt, int buf, int u){
    const int row = u*64 + g_row8;
    const int sc  = ((cg ^ (row & 7)) << 3);
    gload16(A.at(m0 + row, kt*64 + sc), smem + buf*16384 + u*4096 + w*512);
  };
  auto stageB = [&](int kt, int buf, int u){
    const int row = u*64 + g_row8;
    const int sc  = ((cg ^ (row & 7)) << 3);
    gload16(B.at(n0 + row, kt*64 + sc), smem + 49152 + buf*8192 + u*4096 + w*512);
  };

  const int NT = K >> 6;
  #pragma unroll
  for (int u = 0; u < 4; ++u) stageA(0, 0, u);
  #pragma unroll
  for (int u = 0; u < 2; ++u) stageB(0, 0, u);
  #pragma unroll
  for (int u = 0; u < 4; ++u) stageA(1, 1, u);
  #pragma unroll
  for (int u = 0; u < 2; ++u) stageB(1, 1, u);
  asm volatile("s_waitcnt vmcnt(6)" ::: "memory");   // tile 0 landed
  __builtin_amdgcn_s_barrier();
  asm volatile("" ::: "memory");

  int cur = 0;
  for (int kt = 0; kt < NT; ++kt){
    const int tgt = (cur == 0) ? 2 : cur - 1;        // (kt+2) % 3
    const bool pf = (kt + 2 < NT);
    const char* cA = (const char*)(smem + cur * 16384);
    const char* cB = (const char*)(smem + 49152 + cur * 8192);

    auto rdA = [&](int m, int ks)->short8{
      const int r = wm*64 + m*16 + (l & 15);
      const int g = (ks*4 + (l >> 4)) ^ (r & 7);
      return *(const short8*)(cA + r*128 + g*16);
    };
    auto rdB = [&](int n, int ks)->short8{
      const int r = wn*64 + n*16 + (l & 15);
      const int g = (ks*4 + (l >> 4)) ^ (r & 7);
      return *(const short8*)(cB + r*128 + g*16);
    };

    short8 af0a, af0b, af1a, af1b, af2a, af2b, af3a, af3b;
    short8 bf0a, bf0b, bf1a, bf1b, bf2a, bf2b, bf3a, bf3b;

    // ---- phase 0: read af01, bf01; stage A-u0, A-u1; MFMA m01 x n01
    af0a = rdA(0,0); af0b = rdA(0,1); af1a = rdA(1,0); af1b = rdA(1,1);
    bf0a = rdB(0,0); bf0b = rdB(0,1); bf1a = rdB(1,0); bf1b = rdB(1,1);
    if (pf){ stageA(kt+2, tgt, 0); stageA(kt+2, tgt, 1); }
    __builtin_amdgcn_s_barrier();
    __builtin_amdgcn_sched_barrier(0);
    __builtin_amdgcn_s_setprio(1);
    acc[0][0] = MFMA16(af0a, bf0a, acc[0][0]); acc[0][0] = MFMA16(af0b, bf0b, acc[0][0]);
    acc[0][1] = MFMA16(af0a, bf1a, acc[0][1]); acc[0][1] = MFMA16(af0b, bf1b, acc[0][1]);
    acc[1][0] = MFMA16(af1a, bf0a, acc[1][0]); acc[1][0] = MFMA16(af1b, bf0b, acc[1][0]);
    acc[1][1] = MFMA16(af1a, bf1a, acc[1][1]); acc[1][1] = MFMA16(af1b, bf1b, acc[1][1]);
    __builtin_amdgcn_s_setprio(0);
    __builtin_amdgcn_s_barrier();
    asm volatile("" ::: "memory");

    // ---- phase 1: read bf23; stage A-u2, A-u3; MFMA m01 x n23
    bf2a = rdB(2,0); bf2b = rdB(2,1); bf3a = rdB(3,0); bf3b = rdB(3,1);
    if (pf){ stageA(kt+2, tgt, 2); stageA(kt+2, tgt, 3); }
    __builtin_amdgcn_s_barrier();
    __builtin_amdgcn_sched_barrier(0);
    __builtin_amdgcn_s_setprio(1);
    acc[0][2] = MFMA16(af0a, bf2a, acc[0][2]); acc[0][2] = MFMA16(af0b, bf2b, acc[0][2]);
    acc[0][3] = MFMA16(af0a, bf3a, acc[0][3]); acc[0][3] = MFMA16(af0b, bf3b, acc[0][3]);
    acc[1][2] = MFMA16(af1a, bf2a, acc[1][2]); acc[1][2] = MFMA16(af1b, bf2b, acc[1][2]);
    acc[1][3] = MFMA16(af1a, bf3a, acc[1][3]); acc[1][3] = MFMA16(af1b, bf3b, acc[1][3]);
    __builtin_amdgcn_s_setprio(0);
    __builtin_amdgcn_s_barrier();
    asm volatile("" ::: "memory");

    // ---- phase 2: read af23; stage B-u0, B-u1; MFMA m23 x n23
    af2a = rdA(2,0); af2b = rdA(2,1); af3a = rdA(3,0); af3b = rdA(3,1);
    if (pf){ stageB(kt+2, tgt, 0); stageB(kt+2, tgt, 1); }
    __builtin_amdgcn_s_barrier();
    __builtin_amdgcn_sched_barrier(0);
    __builtin_amdgcn_s_setprio(1);
    acc[2][2] = MFMA16(af2a, bf2a, acc[2][2]); acc[2][2] = MFMA16(af2b, bf2b, acc[2][2]);
    acc[2][3] = MFMA16(af2a, bf3a, acc[2][3]); acc[2][3] = MFMA16(af2b, bf3b, acc[2][3]);
    acc[3][2] = MFMA16(af3a, bf2a, acc[3][2]); acc[3][2] = MFMA16(af3b, bf2b, acc[3][2]);
    acc[3][3] = MFMA16(af3a, bf3a, acc[3][3]); acc[3][3] = MFMA16(af3b, bf3b, acc[3][3]);
    __builtin_amdgcn_s_setprio(0);
    __builtin_amdgcn_s_barrier();
    asm volatile("" ::: "memory");

    // ---- phase 3: no new reads/stages; MFMA m23 x n01; K-tile boundary wait
    __builtin_amdgcn_s_setprio(1);
    acc[2][0] = MFMA16(af2a, bf0a, acc[2][0]); acc[2][0] = MFMA16(af2b, bf0b, acc[2][0]);
    acc[2][1] = MFMA16(af2a, bf1a, acc[2][1]); acc[2][1] = MFMA16(af2b, bf1b, acc[2][1]);
    acc[3][0] = MFMA16(af3a, bf0a, acc[3][0]); acc[3][0] = MFMA16(af3b, bf0b, acc[3][0]);
    acc[3][1] = MFMA16(af3a, bf1a, acc[3][1]); acc[3][1] = MFMA16(af3b, bf1b, acc[3][1]);
    __builtin_amdgcn_s_setprio(0);
    if (pf) asm volatile("s_waitcnt vmcnt(6)" ::: "memory");
    else    asm volatile("s_waitcnt vmcnt(0)" ::: "memory");
    __builtin_amdgcn_s_barrier();
    asm volatile("" ::: "memory");
    cur = (cur == 2) ? 0 : cur + 1;
  }
}

#define ACC_INIT(acc) \
  _Pragma("unroll") for (int m_=0;m_<4;m_++) _Pragma("unroll") for (int n_=0;n_<4;n_++) \
    acc[m_][n_] = (f32x4){0.f,0.f,0.f,0.f};

// ---------------------------------------------------------------------------
// f32 -> bf16, 8 elems/thread, grid-stride.
// ---------------------------------------------------------------------------
__global__ __launch_bounds__(256) void cvt_k(
    const float* __restrict__ in, short* __restrict__ out, int n8, float scale)
{
  int i = blockIdx.x * blockDim.x + threadIdx.x;
  const int stride = gridDim.x * blockDim.x;
  for (; i < n8; i += stride){
    floatv4 a = *(const floatv4*)(in + (long)i*8);
    floatv4 b = *(const floatv4*)(in + (long)i*8 + 4);
    short8 s;
    #pragma unroll
    for (int j = 0; j < 4; ++j){ s[j] = f2bf(a[j]*scale); s[4+j] = f2bf(b[j]*scale); }
    *(short8*)(out + (long)i*8) = s;
  }
}

// all 4 weight matrices in one launch; Wq (region 0) pre-scaled by 1/64.
__global__ __launch_bounds__(256) void cvt_w_k(
    const float* __restrict__ Wq, const float* __restrict__ Wk,
    const float* __restrict__ Wv, const float* __restrict__ Wo,
    short* __restrict__ out)
{
  const int i = blockIdx.x * blockDim.x + threadIdx.x;   // 0..294911
  const int wsel = i / 73728, j = i - wsel * 73728;
  const float* src = (wsel == 0) ? Wq : (wsel == 1) ? Wk : (wsel == 2) ? Wv : Wo;
  const float scale = (wsel == 0) ? 0.015625f : 1.0f;
  floatv4 a = *(const floatv4*)(src + (long)j*8);
  floatv4 b = *(const floatv4*)(src + (long)j*8 + 4);
  short8 s;
  #pragma unroll
  for (int q = 0; q < 4; ++q){ s[q] = f2bf(a[q]*scale); s[4+q] = f2bf(b[q]*scale); }
  *(short8*)(out + (long)i*8) = s;
}

// ---------------------------------------------------------------------------
// Projection: out = xb @ W[which]^T + bias, written permuted as
// out[h][pos][r*64+d]. which: 0=q (pre-scaled), 1=k, 2=v. grid (128,6,nz).
// ---------------------------------------------------------------------------
__global__ __launch_bounds__(512, 2) void proj_k(
    const short* __restrict__ xb, const short* __restrict__ wb,
    const float* __restrict__ bq, const float* __restrict__ bk, const float* __restrict__ bv,
    short* __restrict__ outA, short* __restrict__ outB, int zbase)
{
  __shared__ short smem[73728];
  const int which = blockIdx.z + zbase;
  const int m0 = blockIdx.x * 256, n0 = blockIdx.y * 128;

  f32x4 acc[4][4]; ACC_INIT(acc);
  Lin A{xb, E_};
  Lin B{wb + (long)which * E_ * E_, E_};
  gemm_core(A, B, m0, n0, E_, smem, acc);

  const float* bias = (which == 0) ? bq : (which == 1 ? bk : bv);
  short* out = (which == 1) ? outB : outA;
  const float sc = (which == 0) ? 0.015625f : 1.0f;

  const int t = threadIdx.x, l = t & 63, w = t >> 6;
  const int wr = (w >> 1) * 64, wc = (w & 1) * 64;
  #pragma unroll
  for (int n = 0; n < 4; ++n){
    const int gc = n0 + wc + n*16 + (l & 15);
    const float bb = bias[gc] * sc;
    const int h = gc >> 6, d = gc & 63;
    #pragma unroll
    for (int m = 0; m < 4; ++m){
      #pragma unroll
      for (int rg = 0; rg < 4; ++rg){
        const int gm = m0 + wr + m*16 + (l >> 4)*4 + rg;
        const int i = gm & 511, r = gm >> 9;
        out[((long)(h*512 + i))*4096 + r*64 + d] = f2bf(acc[m][n][rg] + bb);
      }
    }
  }
}

// ---------------------------------------------------------------------------
// Logits split-K x2: slice s covers K in [s*2048, (s+1)*2048). grid (2,4,24),
// z = h*2 + s. Partial f32 tiles: s=0 -> probs region, s=1 -> out-region
// scratch (overwritten later by oproj). Diag mask done in softmax.
// ---------------------------------------------------------------------------
__global__ __launch_bounds__(512, 2) void logits_k(
    const short* __restrict__ qt, const short* __restrict__ kt,
    float* __restrict__ probs, float* __restrict__ scratch)
{
  __shared__ short smem[73728];
  const int h = blockIdx.z >> 1, s = blockIdx.z & 1;
  const int m0 = blockIdx.x * 256, n0 = blockIdx.y * 128;

  f32x4 acc[4][4]; ACC_INIT(acc);
  Lin A{qt + (long)h * C_ * 4096 + s*2048, 4096};
  Lin B{kt + (long)h * C_ * 4096 + s*2048, 4096};
  gemm_core(A, B, m0, n0, 2048, smem, acc);

  float* base = (s == 0) ? probs : scratch;
  float* Sh = base + (long)h * C_ * C_;
  const int t = threadIdx.x, l = t & 63, w = t >> 6;
  const int wr = (w >> 1) * 64, wc = (w & 1) * 64;
  #pragma unroll
  for (int m = 0; m < 4; ++m){
    #pragma unroll
    for (int n = 0; n < 4; ++n){
      #pragma unroll
      for (int rg = 0; rg < 4; ++rg){
        const int gi = m0 + wr + m*16 + (l >> 4)*4 + rg;
        const int gj = n0 + wc + n*16 + (l & 15);
        Sh[(long)gi * C_ + gj] = acc[m][n][rg];
      }
    }
  }
}

// ---------------------------------------------------------------------------
// softmax over 512 cols: sum 2 partials, mask diag, softmax.
// Writes f32 probs in place of partial0 + bf16 copy. grid (6144), block 256.
// ---------------------------------------------------------------------------
__global__ __launch_bounds__(256) void softmax4_k(
    float* __restrict__ S0, const float* __restrict__ S1, short* __restrict__ Pbf)
{
  const int row = blockIdx.x;       // h*512 + i
  const int i = row & 511;
  const long base = (long)row * C_;
  const int t = threadIdx.x, lane = t & 63, wid = t >> 6;
  __shared__ float red[4];

  float v0 = S0[base + t]       + S1[base + t];
  float v1 = S0[base + t + 256] + S1[base + t + 256];
  if (t == i)       v0 = -1e9f;
  if (t + 256 == i) v1 = -1e9f;

  float mx = fmaxf(v0, v1);
  #pragma unroll
  for (int m = 1; m < 64; m <<= 1) mx = fmaxf(mx, __shfl_xor(mx, m, 64));
  if (lane == 0) red[wid] = mx;
  __syncthreads();
  mx = fmaxf(fmaxf(red[0], red[1]), fmaxf(red[2], red[3]));
  __syncthreads();

  float e0 = __expf(v0 - mx), e1 = __expf(v1 - mx);
  float ssum = e0 + e1;
  #pragma unroll
  for (int m = 1; m < 64; m <<= 1) ssum += __shfl_xor(ssum, m, 64);
  if (lane == 0) red[wid] = ssum;
  __syncthreads();
  const float inv = 1.0f / (red[0] + red[1] + red[2] + red[3]);

  const float p0 = e0 * inv, p1 = e1 * inv;
  S0[base + t] = p0; S0[base + t + 256] = p1;
  Pbf[base + t] = f2bf(p0);
  Pbf[base + t + 256] = f2bf(p1);
}

// ---------------------------------------------------------------------------
// v transpose per head: vt[h][j][rd] (ld 4096) -> vtt[h][rd][j] (ld 512).
// grid (8 jt, 64 rdt, 12 h).
// ---------------------------------------------------------------------------
__global__ __launch_bounds__(256) void vtrans_k(
    const short* __restrict__ vt, short* __restrict__ vtt)
{
  __shared__ short tile[64][72];
  const int jt = blockIdx.x, rt = blockIdx.y, h = blockIdx.z;
  const int t = threadIdx.x, srow = t >> 2, scb = (t & 3) * 16;

  const short* src = vt + (long)h*C_*4096 + (long)(jt*64 + srow)*4096 + rt*64 + scb;
  *(short8*)&tile[srow][scb]     = *(const short8*)(src);
  *(short8*)&tile[srow][scb + 8] = *(const short8*)(src + 8);
  __syncthreads();
  short tmp[16];
  #pragma unroll
  for (int i = 0; i < 16; ++i) tmp[i] = tile[scb + i][srow];
  short* dst = vtt + (long)h*4096*C_ + (long)(rt*64 + srow)*C_ + jt*64 + scb;
  *(short8*)(dst)     = *(short8*)&tmp[0];
  *(short8*)(dst + 8) = *(short8*)&tmp[8];
}

// ---------------------------------------------------------------------------
// Context: per head, ctx_t[h][i][rd] = P_h[i][:] @ Vtt_h[rd][:]^T (NT, K=512).
// grid (2, 32, 12), bf16 out.
// ---------------------------------------------------------------------------
__global__ __launch_bounds__(512, 2) void ctx_k(
    const short* __restrict__ pb, const short* __restrict__ vtt, short* __restrict__ ctx_t)
{
  __shared__ short smem[73728];
  const int h = blockIdx.z;
  const int m0 = blockIdx.x * 256, n0 = blockIdx.y * 128;

  f32x4 acc[4][4]; ACC_INIT(acc);
  Lin A{pb + (long)h * C_ * C_, C_};
  Lin B{vtt + (long)h * 4096 * C_, C_};
  gemm_core(A, B, m0, n0, C_, smem, acc);

  const int t = threadIdx.x, l = t & 63, w = t >> 6;
  const int wr = (w >> 1) * 64, wc = (w & 1) * 64;
  short* outh = ctx_t + (long)h * C_ * 4096;
  #pragma unroll
  for (int m = 0; m < 4; ++m){
    #pragma unroll
    for (int n = 0; n < 4; ++n){
      #pragma unroll
      for (int rg = 0; rg < 4; ++rg){
        const int gi = m0 + wr + m*16 + (l >> 4)*4 + rg;
        const int gn = n0 + wc + n*16 + (l & 15);
        outh[(long)gi * 4096 + gn] = f2bf(acc[m][n][rg]);
      }
    }
  }
}

// ---------------------------------------------------------------------------
// Output projection: out = ctx @ Wo^T + bo, f32 out. grid (128, 6).
// ---------------------------------------------------------------------------
__global__ __launch_bounds__(512, 2) void oproj_k(
    const short* __restrict__ ctx_t, const short* __restrict__ wo,
    const float* __restrict__ bo, float* __restrict__ out)
{
  __shared__ short smem[73728];
  const int m0 = blockIdx.x * 256, n0 = blockIdx.y * 128;

  f32x4 acc[4][4]; ACC_INIT(acc);
  CtxMap A{ctx_t};
  Lin B{wo, E_};
  gemm_core(A, B, m0, n0, E_, smem, acc);

  const int t = threadIdx.x, l = t & 63, w = t >> 6;
  const int wr = (w >> 1) * 64, wc = (w & 1) * 64;
  #pragma unroll
  for (int n = 0; n < 4; ++n){
    const int gc = n0 + wc + n*16 + (l & 15);
    const float bb = bo[gc];
    #pragma unroll
    for (int m = 0; m < 4; ++m){
      #pragma unroll
      for (int rg = 0; rg < 4; ++rg){
        const int gm = m0 + wr + m*16 + (l >> 4)*4 + rg;
        out[(long)gm * E_ + gc] = acc[m][n][rg] + bb;
      }
    }
  }
}

// ---------------------------------------------------------------------------
extern "C" void kernel_launch(void* const* d_in, const int* in_sizes, int n_in,
                              void* d_out, int out_size, void* d_ws, size_t ws_size,
                              hipStream_t stream)
{
  const float* x  = (const float*)d_in[0];
  const float* Wq = (const float*)d_in[2];
  const float* bq = (const float*)d_in[3];
  const float* Wk = (const float*)d_in[4];
  const float* bk = (const float*)d_in[5];
  const float* Wv = (const float*)d_in[6];
  const float* bv = (const float*)d_in[7];
  const float* Wo = (const float*)d_in[8];
  const float* bo = (const float*)d_in[9];
  const float* l  = (const float*)d_in[10];

  float* out   = (float*)d_out;                          // [32768][768]
  float* probs = out + (size_t)M_TOT * E_;               // [12][512][512] f32
  float* lout  = probs + (size_t)H_ * C_ * C_;           // [12]

  short* ws_s = (short*)d_ws;
  const size_t SLOT = (size_t)M_TOT * E_;                // 25,165,824 elems
  short* s0 = ws_s;                // xb (cvt..proj_v), vtt (vtrans..ctx)
  short* s1 = ws_s + SLOT;         // qt (..logits), vt (proj_v..vtrans), ctx_t (ctx..oproj)
  short* s2 = ws_s + 2*SLOT;       // kt (..logits), pb (softmax..ctx)
  short* wb = ws_s + 3*SLOT;       // 4 x 589824 bf16 weights

  hipMemcpyAsync(lout, l, H_ * sizeof(float), hipMemcpyDeviceToDevice, stream);

  cvt_k<<<2048, 256, 0, stream>>>(x, s0, (int)(SLOT/8), 1.0f);
  cvt_w_k<<<1152, 256, 0, stream>>>(Wq, Wk, Wv, Wo, wb);

  // q,k projections -> logits (split-K x2, partial1 into d_out scratch)
  proj_k<<<dim3(128, 6, 2), 512, 0, stream>>>(s0, wb, bq, bk, bv, s1, s2, 0);
  logits_k<<<dim3(2, 4, 24), 512, 0, stream>>>(s1, s2, probs, out);
  // v projection (overwrites qt), softmax (pb overwrites kt)
  proj_k<<<dim3(128, 6, 1), 512, 0, stream>>>(s0, wb, bq, bk, bv, s1, s2, 2);
  softmax4_k<<<dim3(H_ * C_), 256, 0, stream>>>(probs, out, s2);
  vtrans_k<<<dim3(8, 64, H_), 256, 0, stream>>>(s1, s0);
  ctx_k<<<dim3(2, 32, H_), 512, 0, stream>>>(s2, s0, s1);
  oproj_k<<<dim3(128, 6), 512, 0, stream>>>(s1, wb + 3*589824, bo, out);
}

// Round 5
// 308.033 us; speedup vs baseline: 2.1240x; 1.0909x over previous
//
#include <hip/hip_runtime.h>
#include <stdint.h>

#define R_ 64
#define C_ 512
#define E_ 768
#define H_ 12
#define D_ 64
#define M_TOT (R_*C_)   // 32768

using short4v = __attribute__((ext_vector_type(4))) short;
using short8  = __attribute__((ext_vector_type(8))) short;
using f32x4   = __attribute__((ext_vector_type(4))) float;
using floatv4 = __attribute__((ext_vector_type(4))) float;

#define MFMA16(a,b,c) __builtin_amdgcn_mfma_f32_16x16x32_bf16(a,b,c,0,0,0)

__device__ __forceinline__ short f2bf(float f){
  union { float f; unsigned u; } c; c.f = f;
  unsigned u = c.u;
  u += 0x7fffu + ((u >> 16) & 1u);   // RNE
  return (short)(u >> 16);
}

// async global->LDS, 16B per lane. LDS dest is wave-uniform base; HW adds lane*16.
__device__ __forceinline__ void gload16(const void* g, void* lds){
  __builtin_amdgcn_global_load_lds(
      (const __attribute__((address_space(1))) void*)(uintptr_t)g,
      (__attribute__((address_space(3))) void*)(uint32_t)(uintptr_t)lds,
      16, 0, 0);
}

struct Lin {
  const short* p; int ld;
  __device__ __forceinline__ const short* at(int r, int c) const {
    return p + (long)r * ld + c;
  }
};
// oproj A operand: ctx stored as ctx_t[h][i][r*64+d]; m = r*512+i, k = h*64+d
struct CtxMap {
  const short* p;
  __device__ __forceinline__ const short* at(int m, int k) const {
    return p + ((long)((k >> 6) * 512 + (m & 511))) * 4096 + ((m >> 9) << 6) + (k & 63);
  }
};

// ---------------------------------------------------------------------------
// 4-phase-per-K-tile deep-pipelined GEMM core (unchanged from round 4).
// BM=256, BN=128, BK=64. 512 threads = 8 waves (4M x 2N), wave tile 64x64.
// LDS: A 3 bufs x 32KB, B 3 bufs x 16KB. Stage t+2 spread over phases 0-2;
// counted vmcnt(6) at K-tile boundary only. XOR swizzle both-sides (#21).
// ---------------------------------------------------------------------------
template<class AT, class BT>
__device__ __forceinline__ void gemm_core(
    const AT& A, const BT& B, int m0, int n0, int K,
    short* smem, f32x4 (&acc)[4][4])
{
  const int t = threadIdx.x, l = t & 63, w = t >> 6;
  const int wm = w >> 1, wn = w & 1;
  const int g_row8 = t >> 3;
  const int cg = t & 7;

  auto stageA = [&](int kt, int buf, int u){
    const int row = u*64 + g_row8;
    const int sc  = ((cg ^ (row & 7)) << 3);
    gload16(A.at(m0 + row, kt*64 + sc), smem + buf*16384 + u*4096 + w*512);
  };
  auto stageB = [&](int kt, int buf, int u){
    const int row = u*64 + g_row8;
    const int sc  = ((cg ^ (row & 7)) << 3);
    gload16(B.at(n0 + row, kt*64 + sc), smem + 49152 + buf*8192 + u*4096 + w*512);
  };

  const int NT = K >> 6;
  #pragma unroll
  for (int u = 0; u < 4; ++u) stageA(0, 0, u);
  #pragma unroll
  for (int u = 0; u < 2; ++u) stageB(0, 0, u);
  #pragma unroll
  for (int u = 0; u < 4; ++u) stageA(1, 1, u);
  #pragma unroll
  for (int u = 0; u < 2; ++u) stageB(1, 1, u);
  asm volatile("s_waitcnt vmcnt(6)" ::: "memory");
  __builtin_amdgcn_s_barrier();
  asm volatile("" ::: "memory");

  int cur = 0;
  for (int kt = 0; kt < NT; ++kt){
    const int tgt = (cur == 0) ? 2 : cur - 1;
    const bool pf = (kt + 2 < NT);
    const char* cA = (const char*)(smem + cur * 16384);
    const char* cB = (const char*)(smem + 49152 + cur * 8192);

    auto rdA = [&](int m, int ks)->short8{
      const int r = wm*64 + m*16 + (l & 15);
      const int g = (ks*4 + (l >> 4)) ^ (r & 7);
      return *(const short8*)(cA + r*128 + g*16);
    };
    auto rdB = [&](int n, int ks)->short8{
      const int r = wn*64 + n*16 + (l & 15);
      const int g = (ks*4 + (l >> 4)) ^ (r & 7);
      return *(const short8*)(cB + r*128 + g*16);
    };

    short8 af0a, af0b, af1a, af1b, af2a, af2b, af3a, af3b;
    short8 bf0a, bf0b, bf1a, bf1b, bf2a, bf2b, bf3a, bf3b;

    // phase 0
    af0a = rdA(0,0); af0b = rdA(0,1); af1a = rdA(1,0); af1b = rdA(1,1);
    bf0a = rdB(0,0); bf0b = rdB(0,1); bf1a = rdB(1,0); bf1b = rdB(1,1);
    if (pf){ stageA(kt+2, tgt, 0); stageA(kt+2, tgt, 1); }
    __builtin_amdgcn_s_barrier();
    __builtin_amdgcn_sched_barrier(0);
    __builtin_amdgcn_s_setprio(1);
    acc[0][0] = MFMA16(af0a, bf0a, acc[0][0]); acc[0][0] = MFMA16(af0b, bf0b, acc[0][0]);
    acc[0][1] = MFMA16(af0a, bf1a, acc[0][1]); acc[0][1] = MFMA16(af0b, bf1b, acc[0][1]);
    acc[1][0] = MFMA16(af1a, bf0a, acc[1][0]); acc[1][0] = MFMA16(af1b, bf0b, acc[1][0]);
    acc[1][1] = MFMA16(af1a, bf1a, acc[1][1]); acc[1][1] = MFMA16(af1b, bf1b, acc[1][1]);
    __builtin_amdgcn_s_setprio(0);
    __builtin_amdgcn_s_barrier();
    asm volatile("" ::: "memory");

    // phase 1
    bf2a = rdB(2,0); bf2b = rdB(2,1); bf3a = rdB(3,0); bf3b = rdB(3,1);
    if (pf){ stageA(kt+2, tgt, 2); stageA(kt+2, tgt, 3); }
    __builtin_amdgcn_s_barrier();
    __builtin_amdgcn_sched_barrier(0);
    __builtin_amdgcn_s_setprio(1);
    acc[0][2] = MFMA16(af0a, bf2a, acc[0][2]); acc[0][2] = MFMA16(af0b, bf2b, acc[0][2]);
    acc[0][3] = MFMA16(af0a, bf3a, acc[0][3]); acc[0][3] = MFMA16(af0b, bf3b, acc[0][3]);
    acc[1][2] = MFMA16(af1a, bf2a, acc[1][2]); acc[1][2] = MFMA16(af1b, bf2b, acc[1][2]);
    acc[1][3] = MFMA16(af1a, bf3a, acc[1][3]); acc[1][3] = MFMA16(af1b, bf3b, acc[1][3]);
    __builtin_amdgcn_s_setprio(0);
    __builtin_amdgcn_s_barrier();
    asm volatile("" ::: "memory");

    // phase 2
    af2a = rdA(2,0); af2b = rdA(2,1); af3a = rdA(3,0); af3b = rdA(3,1);
    if (pf){ stageB(kt+2, tgt, 0); stageB(kt+2, tgt, 1); }
    __builtin_amdgcn_s_barrier();
    __builtin_amdgcn_sched_barrier(0);
    __builtin_amdgcn_s_setprio(1);
    acc[2][2] = MFMA16(af2a, bf2a, acc[2][2]); acc[2][2] = MFMA16(af2b, bf2b, acc[2][2]);
    acc[2][3] = MFMA16(af2a, bf3a, acc[2][3]); acc[2][3] = MFMA16(af2b, bf3b, acc[2][3]);
    acc[3][2] = MFMA16(af3a, bf2a, acc[3][2]); acc[3][2] = MFMA16(af3b, bf2b, acc[3][2]);
    acc[3][3] = MFMA16(af3a, bf3a, acc[3][3]); acc[3][3] = MFMA16(af3b, bf3b, acc[3][3]);
    __builtin_amdgcn_s_setprio(0);
    __builtin_amdgcn_s_barrier();
    asm volatile("" ::: "memory");

    // phase 3
    __builtin_amdgcn_s_setprio(1);
    acc[2][0] = MFMA16(af2a, bf0a, acc[2][0]); acc[2][0] = MFMA16(af2b, bf0b, acc[2][0]);
    acc[2][1] = MFMA16(af2a, bf1a, acc[2][1]); acc[2][1] = MFMA16(af2b, bf1b, acc[2][1]);
    acc[3][0] = MFMA16(af3a, bf0a, acc[3][0]); acc[3][0] = MFMA16(af3b, bf0b, acc[3][0]);
    acc[3][1] = MFMA16(af3a, bf1a, acc[3][1]); acc[3][1] = MFMA16(af3b, bf1b, acc[3][1]);
    __builtin_amdgcn_s_setprio(0);
    if (pf) asm volatile("s_waitcnt vmcnt(6)" ::: "memory");
    else    asm volatile("s_waitcnt vmcnt(0)" ::: "memory");
    __builtin_amdgcn_s_barrier();
    asm volatile("" ::: "memory");
    cur = (cur == 2) ? 0 : cur + 1;
  }
}

#define ACC_INIT(acc) \
  _Pragma("unroll") for (int m_=0;m_<4;m_++) _Pragma("unroll") for (int n_=0;n_<4;n_++) \
    acc[m_][n_] = (f32x4){0.f,0.f,0.f,0.f};

// ---------------------------------------------------------------------------
__global__ __launch_bounds__(256) void cvt_k(
    const float* __restrict__ in, short* __restrict__ out, int n8, float scale)
{
  int i = blockIdx.x * blockDim.x + threadIdx.x;
  const int stride = gridDim.x * blockDim.x;
  for (; i < n8; i += stride){
    floatv4 a = *(const floatv4*)(in + (long)i*8);
    floatv4 b = *(const floatv4*)(in + (long)i*8 + 4);
    short8 s;
    #pragma unroll
    for (int j = 0; j < 4; ++j){ s[j] = f2bf(a[j]*scale); s[4+j] = f2bf(b[j]*scale); }
    *(short8*)(out + (long)i*8) = s;
  }
}

__global__ __launch_bounds__(256) void cvt_w_k(
    const float* __restrict__ Wq, const float* __restrict__ Wk,
    const float* __restrict__ Wv, const float* __restrict__ Wo,
    short* __restrict__ out)
{
  const int i = blockIdx.x * blockDim.x + threadIdx.x;
  const int wsel = i / 73728, j = i - wsel * 73728;
  const float* src = (wsel == 0) ? Wq : (wsel == 1) ? Wk : (wsel == 2) ? Wv : Wo;
  const float scale = (wsel == 0) ? 0.015625f : 1.0f;
  floatv4 a = *(const floatv4*)(src + (long)j*8);
  floatv4 b = *(const floatv4*)(src + (long)j*8 + 4);
  short8 s;
  #pragma unroll
  for (int q = 0; q < 4; ++q){ s[q] = f2bf(a[q]*scale); s[4+q] = f2bf(b[q]*scale); }
  *(short8*)(out + (long)i*8) = s;
}

// ---------------------------------------------------------------------------
// All three projections in one launch, XCD-swizzled with full x-panel reuse:
// per XCD, order = mlocal-major, then n, then which -- each x A-panel is
// consumed by 18 consecutive blocks on the same XCD (6 n-tiles x 3 proj).
// q -> qt[h][i][rd] (scaled, W pre-scaled, bias scaled here)
// k -> kt[h][i][rd]
// v -> vtt[h][rd][j] DIRECTLY (transposed write; eliminates vtrans kernel)
// grid: 1-D 2304 blocks of 512.
// ---------------------------------------------------------------------------
__global__ __launch_bounds__(512, 2) void proj_k(
    const short* __restrict__ xb, const short* __restrict__ wb,
    const float* __restrict__ bq, const float* __restrict__ bk, const float* __restrict__ bv,
    short* __restrict__ qt, short* __restrict__ kt, short* __restrict__ vtt)
{
  __shared__ short smem[73728];
  const int bid = blockIdx.x;
  const int xcd = bid & 7, idx = bid >> 3;        // idx 0..287
  const int mlocal = idx / 18, rem = idx % 18;
  const int n = rem / 3, which = rem % 3;
  const int m0 = (xcd * 16 + mlocal) * 256;
  const int n0 = n * 128;

  f32x4 acc[4][4]; ACC_INIT(acc);
  Lin A{xb, E_};
  Lin B{wb + (long)which * E_ * E_, E_};
  gemm_core(A, B, m0, n0, E_, smem, acc);

  const int t = threadIdx.x, l = t & 63, w = t >> 6;
  const int wr = (w >> 1) * 64, wc = (w & 1) * 64;

  if (which == 2){
    // v: direct transposed write vtt[h][r*64+d][j]
    const int r = m0 >> 9;
    #pragma unroll
    for (int nn = 0; nn < 4; ++nn){
      const int gc = n0 + wc + nn*16 + (l & 15);
      const float bb = bv[gc];
      const int h = gc >> 6, d = gc & 63;
      short* dst0 = vtt + ((long)h*4096 + r*64 + d) * 512;
      #pragma unroll
      for (int m = 0; m < 4; ++m){
        const int j0 = (m0 & 511) + wr + m*16 + (l >> 4)*4;
        short4v s;
        #pragma unroll
        for (int rg = 0; rg < 4; ++rg) s[rg] = f2bf(acc[m][nn][rg] + bb);
        *(short4v*)(dst0 + j0) = s;
      }
    }
  } else {
    const float* bias = (which == 0) ? bq : bk;
    short* out = (which == 0) ? qt : kt;
    const float sc = (which == 0) ? 0.015625f : 1.0f;
    #pragma unroll
    for (int nn = 0; nn < 4; ++nn){
      const int gc = n0 + wc + nn*16 + (l & 15);
      const float bb = bias[gc] * sc;
      const int h = gc >> 6, d = gc & 63;
      #pragma unroll
      for (int m = 0; m < 4; ++m){
        #pragma unroll
        for (int rg = 0; rg < 4; ++rg){
          const int gm = m0 + wr + m*16 + (l >> 4)*4 + rg;
          const int i = gm & 511, r = gm >> 9;
          out[((long)(h*512 + i))*4096 + r*64 + d] = f2bf(acc[m][nn][rg] + bb);
        }
      }
    }
  }
}

// ---------------------------------------------------------------------------
// Logits split-K x2. 1-D grid 192; z-grouped on XCDs (3 z per XCD, all 8
// blocks of a z consecutive on one XCD). Both partials -> out-region scratch.
// ---------------------------------------------------------------------------
__global__ __launch_bounds__(512, 2) void logits_k(
    const short* __restrict__ qt, const short* __restrict__ kt,
    float* __restrict__ P0, float* __restrict__ P1)
{
  __shared__ short smem[73728];
  const int bid = blockIdx.x;
  const int xcd = bid & 7, idx = bid >> 3;        // idx 0..23
  const int z = xcd * 3 + idx / 8;                // 0..23
  const int local = idx & 7;
  const int h = z >> 1, s = z & 1;
  const int m0 = (local >> 2) * 256, n0 = (local & 3) * 128;

  f32x4 acc[4][4]; ACC_INIT(acc);
  Lin A{qt + (long)h * C_ * 4096 + s*2048, 4096};
  Lin B{kt + (long)h * C_ * 4096 + s*2048, 4096};
  gemm_core(A, B, m0, n0, 2048, smem, acc);

  float* Sh = ((s == 0) ? P0 : P1) + (long)h * C_ * C_;
  const int t = threadIdx.x, l = t & 63, w = t >> 6;
  const int wr = (w >> 1) * 64, wc = (w & 1) * 64;
  #pragma unroll
  for (int m = 0; m < 4; ++m){
    #pragma unroll
    for (int n = 0; n < 4; ++n){
      #pragma unroll
      for (int rg = 0; rg < 4; ++rg){
        const int gi = m0 + wr + m*16 + (l >> 4)*4 + rg;
        const int gj = n0 + wc + n*16 + (l & 15);
        Sh[(long)gi * C_ + gj] = acc[m][n][rg];
      }
    }
  }
}

// ---------------------------------------------------------------------------
// softmax: sum 2 partials, mask diag, softmax -> probs f32 + bf16 copy.
// ---------------------------------------------------------------------------
__global__ __launch_bounds__(256) void softmax4_k(
    const float* __restrict__ S0, const float* __restrict__ S1,
    float* __restrict__ probs, short* __restrict__ Pbf)
{
  const int row = blockIdx.x;       // h*512 + i
  const int i = row & 511;
  const long base = (long)row * C_;
  const int t = threadIdx.x, lane = t & 63, wid = t >> 6;
  __shared__ float red[4];

  float v0 = S0[base + t]       + S1[base + t];
  float v1 = S0[base + t + 256] + S1[base + t + 256];
  if (t == i)       v0 = -1e9f;
  if (t + 256 == i) v1 = -1e9f;

  float mx = fmaxf(v0, v1);
  #pragma unroll
  for (int m = 1; m < 64; m <<= 1) mx = fmaxf(mx, __shfl_xor(mx, m, 64));
  if (lane == 0) red[wid] = mx;
  __syncthreads();
  mx = fmaxf(fmaxf(red[0], red[1]), fmaxf(red[2], red[3]));
  __syncthreads();

  float e0 = __expf(v0 - mx), e1 = __expf(v1 - mx);
  float ssum = e0 + e1;
  #pragma unroll
  for (int m = 1; m < 64; m <<= 1) ssum += __shfl_xor(ssum, m, 64);
  if (lane == 0) red[wid] = ssum;
  __syncthreads();
  const float inv = 1.0f / (red[0] + red[1] + red[2] + red[3]);

  const float p0 = e0 * inv, p1 = e1 * inv;
  probs[base + t] = p0; probs[base + t + 256] = p1;
  Pbf[base + t] = f2bf(p0);
  Pbf[base + t + 256] = f2bf(p1);
}

// ---------------------------------------------------------------------------
// Context: ctx_t[h][i][rd] = P_h @ Vtt_h^T (NT, K=512). 1-D grid 768,
// h-grouped on XCDs so the P_h A-panels stay L2-resident across 32 n-tiles.
// ---------------------------------------------------------------------------
__global__ __launch_bounds__(512, 2) void ctx_k(
    const short* __restrict__ pb, const short* __restrict__ vtt, short* __restrict__ ctx_t)
{
  __shared__ short smem[73728];
  const int bid = blockIdx.x;
  const int seq = (bid & 7) * 96 + (bid >> 3);    // 0..767
  const int h = seq >> 6, local = seq & 63;
  const int m0 = (local >> 5) * 256, n0 = (local & 31) * 128;

  f32x4 acc[4][4]; ACC_INIT(acc);
  Lin A{pb + (long)h * C_ * C_, C_};
  Lin B{vtt + (long)h * 4096 * C_, C_};
  gemm_core(A, B, m0, n0, C_, smem, acc);

  const int t = threadIdx.x, l = t & 63, w = t >> 6;
  const int wr = (w >> 1) * 64, wc = (w & 1) * 64;
  short* outh = ctx_t + (long)h * C_ * 4096;
  #pragma unroll
  for (int m = 0; m < 4; ++m){
    #pragma unroll
    for (int n = 0; n < 4; ++n){
      #pragma unroll
      for (int rg = 0; rg < 4; ++rg){
        const int gi = m0 + wr + m*16 + (l >> 4)*4 + rg;
        const int gn = n0 + wc + n*16 + (l & 15);
        outh[(long)gi * 4096 + gn] = f2bf(acc[m][n][rg]);
      }
    }
  }
}

// ---------------------------------------------------------------------------
// Output projection: out = ctx @ Wo^T + bo, f32. 1-D grid 768, XCD-swizzled
// n-inner (A-panel reused 6x on one XCD).
// ---------------------------------------------------------------------------
__global__ __launch_bounds__(512, 2) void oproj_k(
    const short* __restrict__ ctx_t, const short* __restrict__ wo,
    const float* __restrict__ bo, float* __restrict__ out)
{
  __shared__ short smem[73728];
  const int bid = blockIdx.x;
  const int xcd = bid & 7, idx = bid >> 3;        // 0..95
  const int m0 = (xcd * 16 + idx / 6) * 256;
  const int n0 = (idx % 6) * 128;

  f32x4 acc[4][4]; ACC_INIT(acc);
  CtxMap A{ctx_t};
  Lin B{wo, E_};
  gemm_core(A, B, m0, n0, E_, smem, acc);

  const int t = threadIdx.x, l = t & 63, w = t >> 6;
  const int wr = (w >> 1) * 64, wc = (w & 1) * 64;
  #pragma unroll
  for (int n = 0; n < 4; ++n){
    const int gc = n0 + wc + n*16 + (l & 15);
    const float bb = bo[gc];
    #pragma unroll
    for (int m = 0; m < 4; ++m){
      #pragma unroll
      for (int rg = 0; rg < 4; ++rg){
        const int gm = m0 + wr + m*16 + (l >> 4)*4 + rg;
        out[(long)gm * E_ + gc] = acc[m][n][rg] + bb;
      }
    }
  }
}

// ---------------------------------------------------------------------------
extern "C" void kernel_launch(void* const* d_in, const int* in_sizes, int n_in,
                              void* d_out, int out_size, void* d_ws, size_t ws_size,
                              hipStream_t stream)
{
  const float* x  = (const float*)d_in[0];
  const float* Wq = (const float*)d_in[2];
  const float* bq = (const float*)d_in[3];
  const float* Wk = (const float*)d_in[4];
  const float* bk = (const float*)d_in[5];
  const float* Wv = (const float*)d_in[6];
  const float* bv = (const float*)d_in[7];
  const float* Wo = (const float*)d_in[8];
  const float* bo = (const float*)d_in[9];
  const float* l  = (const float*)d_in[10];

  float* out   = (float*)d_out;                          // [32768][768]
  float* probs = out + (size_t)M_TOT * E_;               // [12][512][512] f32
  float* lout  = probs + (size_t)H_ * C_ * C_;           // [12]

  // out-region scratch (dead until oproj): two logits partials + vtt
  float* P0  = out;                                      // 12.6 MB
  float* P1  = out + 3145728;                            // 12.6 MB
  short* vtt = (short*)(out + 6291456);                  // 50.3 MB bf16

  short* ws_s = (short*)d_ws;
  const size_t SLOT = (size_t)M_TOT * E_;                // 25,165,824 elems
  short* s0 = ws_s;                // xb
  short* s1 = ws_s + SLOT;         // qt -> ctx_t
  short* s2 = ws_s + 2*SLOT;       // kt -> pb
  short* wb = ws_s + 3*SLOT;       // 4 x 589824 bf16 weights

  hipMemcpyAsync(lout, l, H_ * sizeof(float), hipMemcpyDeviceToDevice, stream);

  cvt_k<<<2048, 256, 0, stream>>>(x, s0, (int)(SLOT/8), 1.0f);
  cvt_w_k<<<1152, 256, 0, stream>>>(Wq, Wk, Wv, Wo, wb);

  proj_k<<<2304, 512, 0, stream>>>(s0, wb, bq, bk, bv, s1, s2, vtt);
  logits_k<<<192, 512, 0, stream>>>(s1, s2, P0, P1);
  softmax4_k<<<H_ * C_, 256, 0, stream>>>(P0, P1, probs, s2);
  ctx_k<<<768, 512, 0, stream>>>(s2, vtt, s1);
  oproj_k<<<768, 512, 0, stream>>>(s1, wb + 3*589824, bo, out);
}

// Round 6
// 295.257 us; speedup vs baseline: 2.2159x; 1.0433x over previous
//
#include <hip/hip_runtime.h>
#include <stdint.h>

#define R_ 64
#define C_ 512
#define E_ 768
#define H_ 12
#define D_ 64
#define M_TOT (R_*C_)   // 32768

using short4v = __attribute__((ext_vector_type(4))) short;
using short8  = __attribute__((ext_vector_type(8))) short;
using f32x4   = __attribute__((ext_vector_type(4))) float;
using floatv4 = __attribute__((ext_vector_type(4))) float;

#define MFMA16(a,b,c) __builtin_amdgcn_mfma_f32_16x16x32_bf16(a,b,c,0,0,0)

__device__ __forceinline__ short f2bf(float f){
  union { float f; unsigned u; } c; c.f = f;
  unsigned u = c.u;
  u += 0x7fffu + ((u >> 16) & 1u);   // RNE
  return (short)(u >> 16);
}

// async global->LDS, 16B per lane. LDS dest is wave-uniform base; HW adds lane*16.
__device__ __forceinline__ void gload16(const void* g, void* lds){
  __builtin_amdgcn_global_load_lds(
      (const __attribute__((address_space(1))) void*)(uintptr_t)g,
      (__attribute__((address_space(3))) void*)(uint32_t)(uintptr_t)lds,
      16, 0, 0);
}

struct Lin {
  const short* p; int ld;
  __device__ __forceinline__ const short* at(int r, int c) const {
    return p + (long)r * ld + c;
  }
};
// oproj A operand: ctx stored as ctx_t[h][i][r*64+d]; m = r*512+i, k = h*64+d
struct CtxMap {
  const short* p;
  __device__ __forceinline__ const short* at(int m, int k) const {
    return p + ((long)((k >> 6) * 512 + (m & 511))) * 4096 + ((m >> 9) << 6) + (k & 63);
  }
};

// ---------------------------------------------------------------------------
// 4-phase-per-K-tile deep-pipelined GEMM core (unchanged; used by logits/ctx/
// oproj). BM=256, BN=128, BK=64. 512 threads = 8 waves (4M x 2N).
// ---------------------------------------------------------------------------
template<class AT, class BT>
__device__ __forceinline__ void gemm_core(
    const AT& A, const BT& B, int m0, int n0, int K,
    short* smem, f32x4 (&acc)[4][4])
{
  const int t = threadIdx.x, l = t & 63, w = t >> 6;
  const int wm = w >> 1, wn = w & 1;
  const int g_row8 = t >> 3;
  const int cg = t & 7;

  auto stageA = [&](int kt, int buf, int u){
    const int row = u*64 + g_row8;
    const int sc  = ((cg ^ (row & 7)) << 3);
    gload16(A.at(m0 + row, kt*64 + sc), smem + buf*16384 + u*4096 + w*512);
  };
  auto stageB = [&](int kt, int buf, int u){
    const int row = u*64 + g_row8;
    const int sc  = ((cg ^ (row & 7)) << 3);
    gload16(B.at(n0 + row, kt*64 + sc), smem + 49152 + buf*8192 + u*4096 + w*512);
  };

  const int NT = K >> 6;
  #pragma unroll
  for (int u = 0; u < 4; ++u) stageA(0, 0, u);
  #pragma unroll
  for (int u = 0; u < 2; ++u) stageB(0, 0, u);
  #pragma unroll
  for (int u = 0; u < 4; ++u) stageA(1, 1, u);
  #pragma unroll
  for (int u = 0; u < 2; ++u) stageB(1, 1, u);
  asm volatile("s_waitcnt vmcnt(6)" ::: "memory");
  __builtin_amdgcn_s_barrier();
  asm volatile("" ::: "memory");

  int cur = 0;
  for (int kt = 0; kt < NT; ++kt){
    const int tgt = (cur == 0) ? 2 : cur - 1;
    const bool pf = (kt + 2 < NT);
    const char* cA = (const char*)(smem + cur * 16384);
    const char* cB = (const char*)(smem + 49152 + cur * 8192);

    auto rdA = [&](int m, int ks)->short8{
      const int r = wm*64 + m*16 + (l & 15);
      const int g = (ks*4 + (l >> 4)) ^ (r & 7);
      return *(const short8*)(cA + r*128 + g*16);
    };
    auto rdB = [&](int n, int ks)->short8{
      const int r = wn*64 + n*16 + (l & 15);
      const int g = (ks*4 + (l >> 4)) ^ (r & 7);
      return *(const short8*)(cB + r*128 + g*16);
    };

    short8 af0a, af0b, af1a, af1b, af2a, af2b, af3a, af3b;
    short8 bf0a, bf0b, bf1a, bf1b, bf2a, bf2b, bf3a, bf3b;

    // phase 0
    af0a = rdA(0,0); af0b = rdA(0,1); af1a = rdA(1,0); af1b = rdA(1,1);
    bf0a = rdB(0,0); bf0b = rdB(0,1); bf1a = rdB(1,0); bf1b = rdB(1,1);
    if (pf){ stageA(kt+2, tgt, 0); stageA(kt+2, tgt, 1); }
    __builtin_amdgcn_s_barrier();
    __builtin_amdgcn_sched_barrier(0);
    __builtin_amdgcn_s_setprio(1);
    acc[0][0] = MFMA16(af0a, bf0a, acc[0][0]); acc[0][0] = MFMA16(af0b, bf0b, acc[0][0]);
    acc[0][1] = MFMA16(af0a, bf1a, acc[0][1]); acc[0][1] = MFMA16(af0b, bf1b, acc[0][1]);
    acc[1][0] = MFMA16(af1a, bf0a, acc[1][0]); acc[1][0] = MFMA16(af1b, bf0b, acc[1][0]);
    acc[1][1] = MFMA16(af1a, bf1a, acc[1][1]); acc[1][1] = MFMA16(af1b, bf1b, acc[1][1]);
    __builtin_amdgcn_s_setprio(0);
    __builtin_amdgcn_s_barrier();
    asm volatile("" ::: "memory");

    // phase 1
    bf2a = rdB(2,0); bf2b = rdB(2,1); bf3a = rdB(3,0); bf3b = rdB(3,1);
    if (pf){ stageA(kt+2, tgt, 2); stageA(kt+2, tgt, 3); }
    __builtin_amdgcn_s_barrier();
    __builtin_amdgcn_sched_barrier(0);
    __builtin_amdgcn_s_setprio(1);
    acc[0][2] = MFMA16(af0a, bf2a, acc[0][2]); acc[0][2] = MFMA16(af0b, bf2b, acc[0][2]);
    acc[0][3] = MFMA16(af0a, bf3a, acc[0][3]); acc[0][3] = MFMA16(af0b, bf3b, acc[0][3]);
    acc[1][2] = MFMA16(af1a, bf2a, acc[1][2]); acc[1][2] = MFMA16(af1b, bf2b, acc[1][2]);
    acc[1][3] = MFMA16(af1a, bf3a, acc[1][3]); acc[1][3] = MFMA16(af1b, bf3b, acc[1][3]);
    __builtin_amdgcn_s_setprio(0);
    __builtin_amdgcn_s_barrier();
    asm volatile("" ::: "memory");

    // phase 2
    af2a = rdA(2,0); af2b = rdA(2,1); af3a = rdA(3,0); af3b = rdA(3,1);
    if (pf){ stageB(kt+2, tgt, 0); stageB(kt+2, tgt, 1); }
    __builtin_amdgcn_s_barrier();
    __builtin_amdgcn_sched_barrier(0);
    __builtin_amdgcn_s_setprio(1);
    acc[2][2] = MFMA16(af2a, bf2a, acc[2][2]); acc[2][2] = MFMA16(af2b, bf2b, acc[2][2]);
    acc[2][3] = MFMA16(af2a, bf3a, acc[2][3]); acc[2][3] = MFMA16(af2b, bf3b, acc[2][3]);
    acc[3][2] = MFMA16(af3a, bf2a, acc[3][2]); acc[3][2] = MFMA16(af3b, bf2b, acc[3][2]);
    acc[3][3] = MFMA16(af3a, bf3a, acc[3][3]); acc[3][3] = MFMA16(af3b, bf3b, acc[3][3]);
    __builtin_amdgcn_s_setprio(0);
    __builtin_amdgcn_s_barrier();
    asm volatile("" ::: "memory");

    // phase 3
    __builtin_amdgcn_s_setprio(1);
    acc[2][0] = MFMA16(af2a, bf0a, acc[2][0]); acc[2][0] = MFMA16(af2b, bf0b, acc[2][0]);
    acc[2][1] = MFMA16(af2a, bf1a, acc[2][1]); acc[2][1] = MFMA16(af2b, bf1b, acc[2][1]);
    acc[3][0] = MFMA16(af3a, bf0a, acc[3][0]); acc[3][0] = MFMA16(af3b, bf0b, acc[3][0]);
    acc[3][1] = MFMA16(af3a, bf1a, acc[3][1]); acc[3][1] = MFMA16(af3b, bf1b, acc[3][1]);
    __builtin_amdgcn_s_setprio(0);
    if (pf) asm volatile("s_waitcnt vmcnt(6)" ::: "memory");
    else    asm volatile("s_waitcnt vmcnt(0)" ::: "memory");
    __builtin_amdgcn_s_barrier();
    asm volatile("" ::: "memory");
    cur = (cur == 2) ? 0 : cur + 1;
  }
}

#define ACC_INIT(acc) \
  _Pragma("unroll") for (int m_=0;m_<4;m_++) _Pragma("unroll") for (int n_=0;n_<4;n_++) \
    acc[m_][n_] = (f32x4){0.f,0.f,0.f,0.f};

// ---------------------------------------------------------------------------
__global__ __launch_bounds__(256) void cvt_k(
    const float* __restrict__ in, short* __restrict__ out, int n8, float scale)
{
  int i = blockIdx.x * blockDim.x + threadIdx.x;
  const int stride = gridDim.x * blockDim.x;
  for (; i < n8; i += stride){
    floatv4 a = *(const floatv4*)(in + (long)i*8);
    floatv4 b = *(const floatv4*)(in + (long)i*8 + 4);
    short8 s;
    #pragma unroll
    for (int j = 0; j < 4; ++j){ s[j] = f2bf(a[j]*scale); s[4+j] = f2bf(b[j]*scale); }
    *(short8*)(out + (long)i*8) = s;
  }
}

__global__ __launch_bounds__(256) void cvt_w_k(
    const float* __restrict__ Wq, const float* __restrict__ Wk,
    const float* __restrict__ Wv, const float* __restrict__ Wo,
    short* __restrict__ out)
{
  const int i = blockIdx.x * blockDim.x + threadIdx.x;
  const int wsel = i / 73728, j = i - wsel * 73728;
  const float* src = (wsel == 0) ? Wq : (wsel == 1) ? Wk : (wsel == 2) ? Wv : Wo;
  const float scale = (wsel == 0) ? 0.015625f : 1.0f;
  floatv4 a = *(const floatv4*)(src + (long)j*8);
  floatv4 b = *(const floatv4*)(src + (long)j*8 + 4);
  short8 s;
  #pragma unroll
  for (int q = 0; q < 4; ++q){ s[q] = f2bf(a[q]*scale); s[4+q] = f2bf(b[q]*scale); }
  *(short8*)(out + (long)i*8) = s;
}

// ---------------------------------------------------------------------------
// Fused q/k/v projection. BM=256, BN=128, BK=32. One staged A (x) tile feeds
// three B operands (Wq/Wk/Wv) and three accumulators: 157 FLOP/staged-byte.
// LDS: A 3 bufs x 16KB at smem + buf*8192 (shorts); B 3 bufs x 24KB
// (3 proj x 8KB) at smem + 24576 + buf*12288 + p*4096. 120 KB total.
// BK=32 rows are 64B; to stay bank-conflict-free, row PAIRS pack into 128B
// lines with slot = ((row&1)*4 + g) ^ (line&7)  (per-16-lane quarter: 2-way).
// 3 phases per K-tile (one proj each, 16 MFMA); 5 gloads/K-tile/wave;
// counted vmcnt(5) at tile boundary. Same 3-slot/2-ahead race-free scheme.
// Grid: 768 blocks (xcd=bid&7; per XCD m-panel outer, 6 n consecutive).
// v epilogue: LDS bounce -> coalesced 128B row writes into vtt[h][rd][j].
// ---------------------------------------------------------------------------
__global__ __launch_bounds__(512, 2) void proj_fused_k(
    const short* __restrict__ xb, const short* __restrict__ wb,
    const float* __restrict__ bq, const float* __restrict__ bk, const float* __restrict__ bv,
    short* __restrict__ qt, short* __restrict__ kt, short* __restrict__ vtt)
{
  __shared__ short smem[61440];
  const int bid = blockIdx.x;
  const int xcd = bid & 7, idx = bid >> 3;        // idx 0..95
  const int mlocal = idx / 6, n = idx % 6;
  const int m0 = (xcd * 16 + mlocal) * 256;
  const int n0 = n * 128;

  const int t = threadIdx.x, l = t & 63, w = t >> 6;
  const int wm = w >> 1, wn = w & 1;

  // lane -> (row, kgroup) inversion for linear global_load_lds staging
  const int lsub = l >> 3;           // line within instr (0..7)
  const int sslot = l & 7;           // slot within line

  Lin A{xb, E_};

  auto stageA = [&](int kt_, int buf, int u){
    const int L = (w*2 + u)*8 + lsub;            // line 0..127
    const int v = sslot ^ (L & 7);
    const int row = L*2 + (v >> 2);
    const int g = v & 3;
    gload16(A.at(m0 + row, kt_*32 + g*8), smem + buf*8192 + (w*2 + u)*512);
  };
  auto stageB = [&](int kt_, int buf, int p){
    const int L = w*8 + lsub;                    // line 0..63
    const int v = sslot ^ (L & 7);
    const int row = L*2 + (v >> 2);
    const int g = v & 3;
    gload16(wb + (long)p*E_*E_ + (long)(n0 + row)*E_ + kt_*32 + g*8,
            smem + 24576 + buf*12288 + p*4096 + w*512);
  };

  f32x4 acc[3][4][4];
  #pragma unroll
  for (int p = 0; p < 3; ++p) ACC_INIT(acc[p]);

  const int NT = E_ / 32;   // 24
  // prologue: tiles 0,1
  stageA(0,0,0); stageA(0,0,1); stageB(0,0,0); stageB(0,0,1); stageB(0,0,2);
  stageA(1,1,0); stageA(1,1,1); stageB(1,1,0); stageB(1,1,1); stageB(1,1,2);
  asm volatile("s_waitcnt vmcnt(5)" ::: "memory");
  __builtin_amdgcn_s_barrier();
  asm volatile("" ::: "memory");

  int cur = 0;
  for (int kt_ = 0; kt_ < NT; ++kt_){
    const int tgt = (cur == 0) ? 2 : cur - 1;
    const bool pf = (kt_ + 2 < NT);
    const char* cA = (const char*)(smem + cur * 8192);
    const char* cB = (const char*)(smem + 24576 + cur * 12288);

    auto rdA = [&](int m)->short8{
      const int r = wm*64 + m*16 + (l & 15);
      const int g = l >> 4;
      const int L = r >> 1;
      const int s = ((r & 1)*4 + g) ^ (L & 7);
      return *(const short8*)(cA + L*128 + s*16);
    };
    auto rdB = [&](int p, int nn)->short8{
      const int r = wn*64 + nn*16 + (l & 15);
      const int g = l >> 4;
      const int L = r >> 1;
      const int s = ((r & 1)*4 + g) ^ (L & 7);
      return *(const short8*)(cB + p*8192 + L*128 + s*16);
    };

    short8 af0, af1, af2, af3, b0, b1, b2, b3;

    // ---- phase 0: proj q. read A frags + Bq frags; stage A u0,u1
    af0 = rdA(0); af1 = rdA(1); af2 = rdA(2); af3 = rdA(3);
    b0 = rdB(0,0); b1 = rdB(0,1); b2 = rdB(0,2); b3 = rdB(0,3);
    if (pf){ stageA(kt_+2, tgt, 0); stageA(kt_+2, tgt, 1); }
    __builtin_amdgcn_s_barrier();
    __builtin_amdgcn_sched_barrier(0);
    __builtin_amdgcn_s_setprio(1);
    acc[0][0][0] = MFMA16(af0, b0, acc[0][0][0]); acc[0][0][1] = MFMA16(af0, b1, acc[0][0][1]);
    acc[0][0][2] = MFMA16(af0, b2, acc[0][0][2]); acc[0][0][3] = MFMA16(af0, b3, acc[0][0][3]);
    acc[0][1][0] = MFMA16(af1, b0, acc[0][1][0]); acc[0][1][1] = MFMA16(af1, b1, acc[0][1][1]);
    acc[0][1][2] = MFMA16(af1, b2, acc[0][1][2]); acc[0][1][3] = MFMA16(af1, b3, acc[0][1][3]);
    acc[0][2][0] = MFMA16(af2, b0, acc[0][2][0]); acc[0][2][1] = MFMA16(af2, b1, acc[0][2][1]);
    acc[0][2][2] = MFMA16(af2, b2, acc[0][2][2]); acc[0][2][3] = MFMA16(af2, b3, acc[0][2][3]);
    acc[0][3][0] = MFMA16(af3, b0, acc[0][3][0]); acc[0][3][1] = MFMA16(af3, b1, acc[0][3][1]);
    acc[0][3][2] = MFMA16(af3, b2, acc[0][3][2]); acc[0][3][3] = MFMA16(af3, b3, acc[0][3][3]);
    __builtin_amdgcn_s_setprio(0);
    __builtin_amdgcn_s_barrier();
    asm volatile("" ::: "memory");

    // ---- phase 1: proj k. read Bk frags; stage B p0,p1
    b0 = rdB(1,0); b1 = rdB(1,1); b2 = rdB(1,2); b3 = rdB(1,3);
    if (pf){ stageB(kt_+2, tgt, 0); stageB(kt_+2, tgt, 1); }
    __builtin_amdgcn_s_barrier();
    __builtin_amdgcn_sched_barrier(0);
    __builtin_amdgcn_s_setprio(1);
    acc[1][0][0] = MFMA16(af0, b0, acc[1][0][0]); acc[1][0][1] = MFMA16(af0, b1, acc[1][0][1]);
    acc[1][0][2] = MFMA16(af0, b2, acc[1][0][2]); acc[1][0][3] = MFMA16(af0, b3, acc[1][0][3]);
    acc[1][1][0] = MFMA16(af1, b0, acc[1][1][0]); acc[1][1][1] = MFMA16(af1, b1, acc[1][1][1]);
    acc[1][1][2] = MFMA16(af1, b2, acc[1][1][2]); acc[1][1][3] = MFMA16(af1, b3, acc[1][1][3]);
    acc[1][2][0] = MFMA16(af2, b0, acc[1][2][0]); acc[1][2][1] = MFMA16(af2, b1, acc[1][2][1]);
    acc[1][2][2] = MFMA16(af2, b2, acc[1][2][2]); acc[1][2][3] = MFMA16(af2, b3, acc[1][2][3]);
    acc[1][3][0] = MFMA16(af3, b0, acc[1][3][0]); acc[1][3][1] = MFMA16(af3, b1, acc[1][3][1]);
    acc[1][3][2] = MFMA16(af3, b2, acc[1][3][2]); acc[1][3][3] = MFMA16(af3, b3, acc[1][3][3]);
    __builtin_amdgcn_s_setprio(0);
    __builtin_amdgcn_s_barrier();
    asm volatile("" ::: "memory");

    // ---- phase 2: proj v. read Bv frags; stage B p2; boundary wait
    b0 = rdB(2,0); b1 = rdB(2,1); b2 = rdB(2,2); b3 = rdB(2,3);
    if (pf){ stageB(kt_+2, tgt, 2); }
    __builtin_amdgcn_s_barrier();
    __builtin_amdgcn_sched_barrier(0);
    __builtin_amdgcn_s_setprio(1);
    acc[2][0][0] = MFMA16(af0, b0, acc[2][0][0]); acc[2][0][1] = MFMA16(af0, b1, acc[2][0][1]);
    acc[2][0][2] = MFMA16(af0, b2, acc[2][0][2]); acc[2][0][3] = MFMA16(af0, b3, acc[2][0][3]);
    acc[2][1][0] = MFMA16(af1, b0, acc[2][1][0]); acc[2][1][1] = MFMA16(af1, b1, acc[2][1][1]);
    acc[2][1][2] = MFMA16(af1, b2, acc[2][1][2]); acc[2][1][3] = MFMA16(af1, b3, acc[2][1][3]);
    acc[2][2][0] = MFMA16(af2, b0, acc[2][2][0]); acc[2][2][1] = MFMA16(af2, b1, acc[2][2][1]);
    acc[2][2][2] = MFMA16(af2, b2, acc[2][2][2]); acc[2][2][3] = MFMA16(af2, b3, acc[2][2][3]);
    acc[2][3][0] = MFMA16(af3, b0, acc[2][3][0]); acc[2][3][1] = MFMA16(af3, b1, acc[2][3][1]);
    acc[2][3][2] = MFMA16(af3, b2, acc[2][3][2]); acc[2][3][3] = MFMA16(af3, b3, acc[2][3][3]);
    __builtin_amdgcn_s_setprio(0);
    if (pf) asm volatile("s_waitcnt vmcnt(5)" ::: "memory");
    else    asm volatile("s_waitcnt vmcnt(0)" ::: "memory");
    __builtin_amdgcn_s_barrier();
    asm volatile("" ::: "memory");
    cur = (cur == 2) ? 0 : cur + 1;
  }

  // ---------------- epilogue ----------------
  const int wr = wm * 64, wc = wn * 64;

  // q, k: scatter (16-lane groups give 32B-contiguous d-runs; measured OK)
  #pragma unroll
  for (int p = 0; p < 2; ++p){
    const float* bias = (p == 0) ? bq : bk;
    short* outp = (p == 0) ? qt : kt;
    const float sc = (p == 0) ? 0.015625f : 1.0f;
    #pragma unroll
    for (int nn = 0; nn < 4; ++nn){
      const int gc = n0 + wc + nn*16 + (l & 15);
      const float bb = bias[gc] * sc;
      const int h = gc >> 6, d = gc & 63;
      #pragma unroll
      for (int m = 0; m < 4; ++m){
        #pragma unroll
        for (int rg = 0; rg < 4; ++rg){
          const int gm = m0 + wr + m*16 + (l >> 4)*4 + rg;
          const int i = gm & 511, r = gm >> 9;
          outp[((long)(h*512 + i))*4096 + r*64 + d] = f2bf(acc[p][m][nn][rg] + bb);
        }
      }
    }
  }

  // v: LDS bounce -> coalesced vtt[h][r*64+d][j] rows.
  // ldsv layout: row d (0..127) x 512B, 16B-chunk c swizzled c^(d&31).
  {
    short* ldsv = smem;
    #pragma unroll
    for (int nn = 0; nn < 4; ++nn){
      const int dl = wc + nn*16 + (l & 15);
      const float bb = bv[n0 + dl];
      #pragma unroll
      for (int m = 0; m < 4; ++m){
        const int j = wr + m*16 + (l >> 4)*4;
        short4v s;
        #pragma unroll
        for (int rg = 0; rg < 4; ++rg) s[rg] = f2bf(acc[2][m][nn][rg] + bb);
        // 8B write at (dl, j): chunk = j>>3 swizzled, offset (j&7)
        const int byteoff = dl*512 + (((j >> 3) ^ (dl & 31)) << 4) + (j & 7)*2;
        *(short4v*)((char*)ldsv + byteoff) = s;
      }
    }
    __builtin_amdgcn_s_barrier();
    const int dl = t & 127, chunk = t >> 7;     // 4 chunks of 64 shorts
    const int gd = n0 + dl;
    const int h = gd >> 6, dd = gd & 63;
    const int r = m0 >> 9, i0 = m0 & 511;
    short* dst = vtt + ((long)h*4096 + r*64 + dd)*512 + i0 + chunk*64;
    #pragma unroll
    for (int q = 0; q < 8; ++q){
      const int c16 = chunk*8 + q;
      short8 vv = *(const short8*)((const char*)ldsv + dl*512 + ((c16 ^ (dl & 31)) << 4));
      *(short8*)(dst + q*8) = vv;
    }
  }
}

// ---------------------------------------------------------------------------
// Logits split-K x2. 1-D grid 192; z-grouped on XCDs. Partials -> out scratch.
// ---------------------------------------------------------------------------
__global__ __launch_bounds__(512, 2) void logits_k(
    const short* __restrict__ qt, const short* __restrict__ kt,
    float* __restrict__ P0, float* __restrict__ P1)
{
  __shared__ short smem[73728];
  const int bid = blockIdx.x;
  const int xcd = bid & 7, idx = bid >> 3;        // idx 0..23
  const int z = xcd * 3 + idx / 8;                // 0..23
  const int local = idx & 7;
  const int h = z >> 1, s = z & 1;
  const int m0 = (local >> 2) * 256, n0 = (local & 3) * 128;

  f32x4 acc[4][4]; ACC_INIT(acc);
  Lin A{qt + (long)h * C_ * 4096 + s*2048, 4096};
  Lin B{kt + (long)h * C_ * 4096 + s*2048, 4096};
  gemm_core(A, B, m0, n0, 2048, smem, acc);

  float* Sh = ((s == 0) ? P0 : P1) + (long)h * C_ * C_;
  const int t = threadIdx.x, l = t & 63, w = t >> 6;
  const int wr = (w >> 1) * 64, wc = (w & 1) * 64;
  #pragma unroll
  for (int m = 0; m < 4; ++m){
    #pragma unroll
    for (int n = 0; n < 4; ++n){
      #pragma unroll
      for (int rg = 0; rg < 4; ++rg){
        const int gi = m0 + wr + m*16 + (l >> 4)*4 + rg;
        const int gj = n0 + wc + n*16 + (l & 15);
        Sh[(long)gi * C_ + gj] = acc[m][n][rg];
      }
    }
  }
}

// ---------------------------------------------------------------------------
__global__ __launch_bounds__(256) void softmax4_k(
    const float* __restrict__ S0, const float* __restrict__ S1,
    float* __restrict__ probs, short* __restrict__ Pbf)
{
  const int row = blockIdx.x;       // h*512 + i
  const int i = row & 511;
  const long base = (long)row * C_;
  const int t = threadIdx.x, lane = t & 63, wid = t >> 6;
  __shared__ float red[4];

  float v0 = S0[base + t]       + S1[base + t];
  float v1 = S0[base + t + 256] + S1[base + t + 256];
  if (t == i)       v0 = -1e9f;
  if (t + 256 == i) v1 = -1e9f;

  float mx = fmaxf(v0, v1);
  #pragma unroll
  for (int m = 1; m < 64; m <<= 1) mx = fmaxf(mx, __shfl_xor(mx, m, 64));
  if (lane == 0) red[wid] = mx;
  __syncthreads();
  mx = fmaxf(fmaxf(red[0], red[1]), fmaxf(red[2], red[3]));
  __syncthreads();

  float e0 = __expf(v0 - mx), e1 = __expf(v1 - mx);
  float ssum = e0 + e1;
  #pragma unroll
  for (int m = 1; m < 64; m <<= 1) ssum += __shfl_xor(ssum, m, 64);
  if (lane == 0) red[wid] = ssum;
  __syncthreads();
  const float inv = 1.0f / (red[0] + red[1] + red[2] + red[3]);

  const float p0 = e0 * inv, p1 = e1 * inv;
  probs[base + t] = p0; probs[base + t + 256] = p1;
  Pbf[base + t] = f2bf(p0);
  Pbf[base + t + 256] = f2bf(p1);
}

// ---------------------------------------------------------------------------
__global__ __launch_bounds__(512, 2) void ctx_k(
    const short* __restrict__ pb, const short* __restrict__ vtt, short* __restrict__ ctx_t)
{
  __shared__ short smem[73728];
  const int bid = blockIdx.x;
  const int seq = (bid & 7) * 96 + (bid >> 3);    // 0..767
  const int h = seq >> 6, local = seq & 63;
  const int m0 = (local >> 5) * 256, n0 = (local & 31) * 128;

  f32x4 acc[4][4]; ACC_INIT(acc);
  Lin A{pb + (long)h * C_ * C_, C_};
  Lin B{vtt + (long)h * 4096 * C_, C_};
  gemm_core(A, B, m0, n0, C_, smem, acc);

  const int t = threadIdx.x, l = t & 63, w = t >> 6;
  const int wr = (w >> 1) * 64, wc = (w & 1) * 64;
  short* outh = ctx_t + (long)h * C_ * 4096;
  #pragma unroll
  for (int m = 0; m < 4; ++m){
    #pragma unroll
    for (int n = 0; n < 4; ++n){
      #pragma unroll
      for (int rg = 0; rg < 4; ++rg){
        const int gi = m0 + wr + m*16 + (l >> 4)*4 + rg;
        const int gn = n0 + wc + n*16 + (l & 15);
        outh[(long)gi * 4096 + gn] = f2bf(acc[m][n][rg]);
      }
    }
  }
}

// ---------------------------------------------------------------------------
__global__ __launch_bounds__(512, 2) void oproj_k(
    const short* __restrict__ ctx_t, const short* __restrict__ wo,
    const float* __restrict__ bo, float* __restrict__ out)
{
  __shared__ short smem[73728];
  const int bid = blockIdx.x;
  const int xcd = bid & 7, idx = bid >> 3;        // 0..95
  const int m0 = (xcd * 16 + idx / 6) * 256;
  const int n0 = (idx % 6) * 128;

  f32x4 acc[4][4]; ACC_INIT(acc);
  CtxMap A{ctx_t};
  Lin B{wo, E_};
  gemm_core(A, B, m0, n0, E_, smem, acc);

  const int t = threadIdx.x, l = t & 63, w = t >> 6;
  const int wr = (w >> 1) * 64, wc = (w & 1) * 64;
  #pragma unroll
  for (int n = 0; n < 4; ++n){
    const int gc = n0 + wc + n*16 + (l & 15);
    const float bb = bo[gc];
    #pragma unroll
    for (int m = 0; m < 4; ++m){
      #pragma unroll
      for (int rg = 0; rg < 4; ++rg){
        const int gm = m0 + wr + m*16 + (l >> 4)*4 + rg;
        out[(long)gm * E_ + gc] = acc[m][n][rg] + bb;
      }
    }
  }
}

// ---------------------------------------------------------------------------
extern "C" void kernel_launch(void* const* d_in, const int* in_sizes, int n_in,
                              void* d_out, int out_size, void* d_ws, size_t ws_size,
                              hipStream_t stream)
{
  const float* x  = (const float*)d_in[0];
  const float* Wq = (const float*)d_in[2];
  const float* bq = (const float*)d_in[3];
  const float* Wk = (const float*)d_in[4];
  const float* bk = (const float*)d_in[5];
  const float* Wv = (const float*)d_in[6];
  const float* bv = (const float*)d_in[7];
  const float* Wo = (const float*)d_in[8];
  const float* bo = (const float*)d_in[9];
  const float* l  = (const float*)d_in[10];

  float* out   = (float*)d_out;                          // [32768][768]
  float* probs = out + (size_t)M_TOT * E_;               // [12][512][512] f32
  float* lout  = probs + (size_t)H_ * C_ * C_;           // [12]

  // out-region scratch (dead until oproj): two logits partials + vtt
  float* P0  = out;                                      // 12.6 MB
  float* P1  = out + 3145728;                            // 12.6 MB
  short* vtt = (short*)(out + 6291456);                  // 50.3 MB bf16

  short* ws_s = (short*)d_ws;
  const size_t SLOT = (size_t)M_TOT * E_;                // 25,165,824 elems
  short* s0 = ws_s;                // xb
  short* s1 = ws_s + SLOT;         // qt -> ctx_t
  short* s2 = ws_s + 2*SLOT;       // kt -> pb
  short* wb = ws_s + 3*SLOT;       // 4 x 589824 bf16 weights

  hipMemcpyAsync(lout, l, H_ * sizeof(float), hipMemcpyDeviceToDevice, stream);

  cvt_k<<<2048, 256, 0, stream>>>(x, s0, (int)(SLOT/8), 1.0f);
  cvt_w_k<<<1152, 256, 0, stream>>>(Wq, Wk, Wv, Wo, wb);

  proj_fused_k<<<768, 512, 0, stream>>>(s0, wb, bq, bk, bv, s1, s2, vtt);
  logits_k<<<192, 512, 0, stream>>>(s1, s2, P0, P1);
  softmax4_k<<<H_ * C_, 256, 0, stream>>>(P0, P1, probs, s2);
  ctx_k<<<768, 512, 0, stream>>>(s2, vtt, s1);
  oproj_k<<<768, 512, 0, stream>>>(s1, wb + 3*589824, bo, out);
}